// Round 14
// baseline (539.468 us; speedup 1.0000x reference)
//
#include <hip/hip_runtime.h>
#include <hip/hip_bf16.h>
#include <math.h>

// Problem dims
#define B_   256
#define N_   196
#define IN_  1024
#define D_   256
#define H_   8
#define HD_  32
#define NC_  1000
#define S0_  10
#define S1_  20
#define ROWS (B_*N_)      // 50176
#define CAT  (IN_+D_)     // 1280

typedef unsigned short ushort_t;
typedef short bf16x8 __attribute__((ext_vector_type(8)));
typedef float f32x4  __attribute__((ext_vector_type(4)));
typedef ushort_t us4 __attribute__((ext_vector_type(4)));
typedef ushort_t us8 __attribute__((ext_vector_type(8)));

__device__ __forceinline__ ushort_t f2bf(float f){
    __hip_bfloat16 b = __float2bfloat16(f);
    ushort_t u; __builtin_memcpy(&u, &b, 2); return u;
}
__device__ __forceinline__ float bf2f(ushort_t h){
    union { unsigned int u; float f; } x; x.u = ((unsigned int)h) << 16;
    return x.f;
}
__device__ __forceinline__ float gelu_tanh(float x){
    float x3 = x*x*x;
    float inner = 0.7978845608028654f*(x + 0.044715f*x3);
    return 0.5f*x*(1.0f + tanhf(inner));
}

// ---------- async global->LDS, 16B per lane ----------
typedef __attribute__((address_space(1))) const unsigned int gu32;
typedef __attribute__((address_space(3))) unsigned int lu32;
__device__ __forceinline__ void gload_lds16b(const void* g, void* l){
    __builtin_amdgcn_global_load_lds((gu32*)g, (lu32*)l, 16, 0, 0);
}
// swizzle (refcheck'd r4-r13): LDS(row, slot') holds global (row, slot' ^ ((row>>1)&3));
// slots are 16B units; frag read XORs back.
__device__ __forceinline__ bf16x8 frag32(const ushort_t* lds, int row, int fq){
    return *(const bf16x8*)&lds[row*32 + ((fq ^ ((row >> 1) & 3)) << 3)];
}

// ---------- f32 -> bf16 convert for h (8 elems/thread) ----------
__global__ __launch_bounds__(256)
void cvt8_kernel(const float* __restrict__ src, ushort_t* __restrict__ dst)
{
    size_t i = ((size_t)blockIdx.x*256 + threadIdx.x)*8;
    float4 a = *(const float4*)(src + i);
    float4 b = *(const float4*)(src + i + 4);
    us8 o;
    o[0]=f2bf(a.x); o[1]=f2bf(a.y); o[2]=f2bf(a.z); o[3]=f2bf(a.w);
    o[4]=f2bf(b.x); o[5]=f2bf(b.y); o[6]=f2bf(b.z); o[7]=f2bf(b.w);
    *(us8*)(dst + i) = o;
}

// ---------- fused weight prep: Wp/Wsub/Wfs converts + colsum(Wfs); grid 3392 ----------
__global__ __launch_bounds__(256)
void prep_kernel(const float* __restrict__ Wp, const float* __restrict__ Wsub,
                 const float* __restrict__ Wfs,
                 ushort_t* __restrict__ WpsH, ushort_t* __restrict__ WfsH,
                 float* __restrict__ wsum)
{
    const int b = blockIdx.x, t = threadIdx.x;
    if (b < 1024){ int i=b*256+t; WpsH[i] = f2bf(Wp[i]); }
    else if (b < 2048){ int i=(b-1024)*256+t; WpsH[262144+i] = f2bf(Wsub[i]); }
    else if (b < 3328){ int i=(b-2048)*256+t; WfsH[i] = f2bf(Wfs[i]); }
    else {
        int d = (b-3328)*4 + (t>>6), l = t & 63;
        const float* w = Wfs + (size_t)d*CAT;
        float s = 0.f;
        #pragma unroll
        for (int c0=0;c0<CAT;c0+=256){
            float4 v = *(const float4*)(w + c0 + l*4);
            s += v.x+v.y+v.z+v.w;
        }
        #pragma unroll
        for (int off=32;off>0;off>>=1) s += __shfl_down(s, off);
        if (l == 0) wsum[d] = s;
    }
}

// ---------- Wqk[c][d] = s*Σ_e Wq[e][d]·Wk[e][c];  bqk[c] = s*Σ_e bq[e]·Wk[e][c] ----------
__global__ __launch_bounds__(256)
void wqk_kernel(const float* __restrict__ Wq, const float* __restrict__ Wk,
                const float* __restrict__ bq,
                ushort_t* __restrict__ WqkH, float* __restrict__ bqk)
{
    const int c = blockIdx.x, d = threadIdx.x;
    const float s = 0.17677669529663687f; // 32^-0.5 folded
    float acc = 0.f, accb = 0.f;
    for (int e = 0; e < 256; ++e){
        float wkc = Wk[e*256 + c];
        acc  += Wq[e*256 + d] * wkc;
        accb += bq[e] * wkc;
    }
    WqkH[c*256 + d] = f2bf(acc * s);
    if (d == 0) bqk[c] = accb * s;
}

// ---------- Wvo[e2][c] = Σ_e Wo[e2][e]·Wv[e][c];  bvo[e2] = Wo[e2]·bv + bo[e2] ----------
__global__ __launch_bounds__(256)
void wvo_kernel(const float* __restrict__ Wo, const float* __restrict__ Wv,
                const float* __restrict__ bv, const float* __restrict__ bo,
                ushort_t* __restrict__ WvoH, float* __restrict__ bvo)
{
    const int e2 = blockIdx.x, c = threadIdx.x;
    float acc = 0.f, accb = 0.f;
    for (int e = 0; e < 256; ++e){
        float woe = Wo[e2*256 + e];
        acc  += woe * Wv[e*256 + c];
        accb += woe * bv[e];
    }
    WvoH[e2*256 + c] = f2bf(acc);
    if (c == 0) bvo[e2] = accb + bo[e2];
}

// ---------- 3-deep counted-vmcnt pipelined bf16 GEMM (addr-hoisted + setprio) ----------
// 128x256 tile, 8 waves (2x4), BK=32, 3 LDS buffers (72KB).
// EPI: 7=pese(gelu; col<256->pe o1h, else seF f32o + se o2h)
//      3=plain bf16(o1h)  5=fs(LN-fold->f32o)
template<int KCH, int KCH1, int NBN, int EPI>
__global__ __launch_bounds__(512, 4)
void gemm_bf(const ushort_t* __restrict__ A1b, const ushort_t* __restrict__ A2b,
             int lda1, int lda2,
             const ushort_t* __restrict__ BH, int ldb,
             const float* __restrict__ bias1, const float* __restrict__ bias2,
             float* __restrict__ f32o, ushort_t* __restrict__ o1h, ushort_t* __restrict__ o2h,
             const float* __restrict__ rowm, const float* __restrict__ rowr,
             const float* __restrict__ wsump)
{
    __shared__ ushort_t SA[3][128*32];   // 3 x 8 KB
    __shared__ ushort_t SB[3][256*32];   // 3 x 16 KB
    const int nwg = gridDim.x, cpx = nwg >> 3, bid = blockIdx.x;
    const int wg = (bid & 7)*cpx + (bid >> 3);
    const int bn = (wg % NBN)*256, bm = (wg / NBN)*128;
    const int t = threadIdx.x, lane = t & 63, wid = t >> 6;
    const int wr = wid >> 2, wc = wid & 3, fr = lane & 15, fq = lane >> 4;

    // hoisted per-lane staging pointers; advance 64B (=32 ushorts) per staged chunk
    const int rr = lane >> 2;
    const int sl = (lane & 3) ^ ((lane >> 3) & 3);
    const ushort_t* srcA  = A1b + (size_t)(bm + wid*16 + rr)*lda1 + sl*8;
    const ushort_t* srcB0 = BH  + (size_t)(bn + wid*32 + rr)*ldb  + sl*8;
    const ushort_t* srcB1 = srcB0 + (size_t)16*ldb;

    f32x4 acc[4][4];
    #pragma unroll
    for (int i=0;i<4;++i)
        #pragma unroll
        for (int j=0;j<4;++j) acc[i][j] = (f32x4){0.f,0.f,0.f,0.f};

    auto stageT = [&](int buf, int kc){     // 3 vmem instrs per wave
        if (KCH1 < KCH && kc == KCH1)
            srcA = A2b + (size_t)(bm + wid*16 + rr)*lda2 + sl*8;
        gload_lds16b(srcA,  &SA[buf][wid*512]);
        gload_lds16b(srcB0, &SB[buf][wid*1024]);
        gload_lds16b(srcB1, &SB[buf][wid*1024 + 512]);
        srcA += 32; srcB0 += 32; srcB1 += 32;
    };
    auto compute = [&](int buf){
        bf16x8 a[4], b[4];
        #pragma unroll
        for (int i=0;i<4;++i){
            a[i] = frag32(SA[buf], wr*64 + i*16 + fr, fq);
            b[i] = frag32(SB[buf], wc*64 + i*16 + fr, fq);
        }
        __builtin_amdgcn_s_setprio(1);
        #pragma unroll
        for (int i=0;i<4;++i)
            #pragma unroll
            for (int j=0;j<4;++j)
                acc[i][j] = __builtin_amdgcn_mfma_f32_16x16x32_bf16(a[i], b[j], acc[i][j], 0,0,0);
        __builtin_amdgcn_s_setprio(0);
    };

    // prologue: 3 tiles in flight; wait only tile 0
    stageT(0, 0);
    stageT(1, 1);
    stageT(2, 2);
    asm volatile("s_waitcnt vmcnt(6)" ::: "memory");
    __builtin_amdgcn_sched_barrier(0);
    __builtin_amdgcn_s_barrier();

    int cur = 0;
    for (int kc = 0; kc < KCH; ++kc){
        compute(cur);
        if (kc + 1 >= KCH) break;
        asm volatile("s_waitcnt lgkmcnt(0)" ::: "memory");   // this wave's ds_reads retired
        __builtin_amdgcn_s_barrier();                        // all waves done reading buf cur
        if (kc + 3 < KCH){
            stageT(cur, kc + 3);                             // refill freed buffer
            asm volatile("s_waitcnt vmcnt(6)" ::: "memory"); // wait tile kc+1 only
        } else if (kc + 2 < KCH){
            asm volatile("s_waitcnt vmcnt(3)" ::: "memory");
        } else {
            asm volatile("s_waitcnt vmcnt(0)" ::: "memory");
        }
        __builtin_amdgcn_sched_barrier(0);
        __builtin_amdgcn_s_barrier();                        // tile kc+1 visible to all
        cur = (cur == 2) ? 0 : cur + 1;
    }

    // epilogue
    #pragma unroll
    for (int i=0;i<4;++i){
        #pragma unroll
        for (int j=0;j<4;++j){
            const int col = bn + wc*64 + j*16 + fr;
            #pragma unroll
            for (int r=0;r<4;++r){
                const int row = bm + wr*64 + i*16 + fq*4 + r;
                float x = acc[i][j][r];
                if (EPI == 7){
                    if (col < 256){
                        float y = gelu_tanh(x + bias1[col]);
                        o1h[(size_t)row*D_ + col] = f2bf(y);
                    } else {
                        float y = gelu_tanh(x + bias2[col-256]);
                        f32o[(size_t)row*D_ + (col-256)] = y;
                        o2h[(size_t)row*D_ + (col-256)] = f2bf(y);
                    }
                } else if (EPI == 3){
                    o1h[(size_t)row*D_ + col] = f2bf(x + bias1[col]);
                } else { // EPI == 5
                    f32o[(size_t)row*D_ + col] = rowr[row]*(x - rowm[row]*wsump[col]) + bias1[col];
                }
            }
        }
    }
}

// ---------- MFMA attention (bf16 in, bf16 out); K and V are both se ----------
#define KROWS 208
#define KLD   40
#define VLD   232

__global__ __launch_bounds__(256)
void attn_mfma(const ushort_t* __restrict__ qhi,
               const ushort_t* __restrict__ khi,
               const ushort_t* __restrict__ vhi,
               ushort_t* __restrict__ aohi)
{
    __shared__ ushort_t Khi[KROWS*KLD];
    __shared__ ushort_t Vthi[32*VLD];

    const int b = blockIdx.x, hh = blockIdx.y;
    const int t = threadIdx.x;
    const int lane = t & 63;
    const int wid  = t >> 6;
    const int fr = lane & 15;
    const int fq = lane >> 4;
    const size_t bbase = (size_t)b*N_*D_ + hh*HD_;

    for (int idx = t; idx < KROWS*4; idx += 256){
        int row = idx >> 2, c8 = (idx & 3) << 3;
        us8 vh;
        if (row < N_){
            vh = *(const us8*)(khi + bbase + (size_t)row*D_ + c8);
        } else {
            #pragma unroll
            for (int j=0;j<8;++j) vh[j]=0;
        }
        *(us8*)&Khi[row*KLD + c8] = vh;
    }
    for (int idx = t; idx < 224*4; idx += 256){
        int key = idx >> 2, c8 = (idx & 3) << 3;
        us8 vh;
        if (key < N_){
            vh = *(const us8*)(vhi + bbase + (size_t)key*D_ + c8);
        } else {
            #pragma unroll
            for (int j=0;j<8;++j) vh[j]=0;
        }
        int w = key & 31, cc = key >> 5;
        int slot;
        if (w < 16) slot = cc*32 + (w>>2)*8 + (w&3);
        else { int w2 = w-16; slot = cc*32 + (w2>>2)*8 + 4 + (w2&3); }
        #pragma unroll
        for (int j=0;j<8;++j)
            Vthi[(c8 + j)*VLD + slot] = vh[j];
    }
    __syncthreads();

    for (int qt = wid; qt < 13; qt += 4){
        int qrow = qt*16 + fr; if (qrow > N_-1) qrow = N_-1;
        const bf16x8 qh = *(const bf16x8*)(qhi + bbase + (size_t)qrow*D_ + fq*8);

        f32x4 s[13];
        #pragma unroll
        for (int kt=0; kt<13; ++kt) s[kt] = (f32x4){0.f,0.f,0.f,0.f};
        #pragma unroll
        for (int kt=0; kt<13; ++kt){
            const bf16x8 kh = *(const bf16x8*)&Khi[(kt*16 + fr)*KLD + fq*8];
            s[kt] = __builtin_amdgcn_mfma_f32_16x16x32_bf16(kh, qh, s[kt], 0,0,0);
        }
        if (fq > 0) s[12] = (f32x4){-1e30f,-1e30f,-1e30f,-1e30f};

        float m = -3.4e38f;
        #pragma unroll
        for (int kt=0; kt<13; ++kt)
            #pragma unroll
            for (int r=0;r<4;++r) m = fmaxf(m, s[kt][r]);
        m = fmaxf(m, __shfl_xor(m, 16));
        m = fmaxf(m, __shfl_xor(m, 32));
        float sum = 0.f;
        #pragma unroll
        for (int kt=0; kt<13; ++kt)
            #pragma unroll
            for (int r=0;r<4;++r){
                float p = __expf(s[kt][r] - m);
                s[kt][r] = p; sum += p;
            }
        sum += __shfl_xor(sum, 16);
        sum += __shfl_xor(sum, 32);
        const float inv = 1.0f / sum;

        f32x4 o0 = (f32x4){0.f,0.f,0.f,0.f};
        f32x4 o1 = (f32x4){0.f,0.f,0.f,0.f};
        #pragma unroll
        for (int c=0;c<7;++c){
            bf16x8 ph;
            #pragma unroll
            for (int r=0;r<4;++r){
                ph[r]   = (short)f2bf(s[2*c][r]);
                ph[4+r] = (short)((c < 6) ? f2bf(s[2*c+1][r]) : 0);
            }
            const int coff = c*32 + fq*8;
            const bf16x8 v0h = *(const bf16x8*)&Vthi[(fr)*VLD + coff];
            const bf16x8 v1h = *(const bf16x8*)&Vthi[(16+fr)*VLD + coff];
            o0 = __builtin_amdgcn_mfma_f32_16x16x32_bf16(v0h, ph, o0, 0,0,0);
            o1 = __builtin_amdgcn_mfma_f32_16x16x32_bf16(v1h, ph, o1, 0,0,0);
        }
        int tok = qt*16 + fr;
        if (tok < N_){
            const size_t obase = bbase + (size_t)tok*D_;
            #pragma unroll
            for (int r=0;r<4;++r){
                aohi[obase + fq*4 + r]      = f2bf(o0[r]*inv);
                aohi[obase + 16 + fq*4 + r] = f2bf(o1[r]*inv);
            }
        }
    }
}

// ---------- fused rowstats + abar partial, wave-per-row (f32 h + bf16 integ) ----------
#define APLD 1344
__global__ __launch_bounds__(256)
void abar_part(const float* __restrict__ h, const ushort_t* __restrict__ integb,
               float* __restrict__ rowm, float* __restrict__ rowr,
               float* __restrict__ Apart)
{
    const int b = blockIdx.x, qq = blockIdx.y, t = threadIdx.x;
    const int l = t & 63, w = t >> 6;
    const int n0 = qq*49;
    float4 acc[5];
    #pragma unroll
    for (int ch=0; ch<5; ++ch) acc[ch] = (float4){0.f,0.f,0.f,0.f};
    float mracc = 0.f;
    for (int n = w; n < 49; n += 4){
        const int row = b*N_ + n0 + n;
        const float* hr = h + (size_t)row*IN_;
        float4 e[5];
        #pragma unroll
        for (int ch=0; ch<4; ++ch) e[ch] = *(const float4*)(hr + ch*256 + l*4);
        {
            us4 iv = *(const us4*)(integb + (size_t)row*D_ + l*4);
            e[4].x = bf2f(iv[0]); e[4].y = bf2f(iv[1]);
            e[4].z = bf2f(iv[2]); e[4].w = bf2f(iv[3]);
        }
        float s = 0.f, s2 = 0.f;
        #pragma unroll
        for (int ch=0; ch<5; ++ch){
            s  += e[ch].x + e[ch].y + e[ch].z + e[ch].w;
            s2 += e[ch].x*e[ch].x + e[ch].y*e[ch].y + e[ch].z*e[ch].z + e[ch].w*e[ch].w;
        }
        #pragma unroll
        for (int off=32; off>0; off>>=1){ s += __shfl_xor(s, off); s2 += __shfl_xor(s2, off); }
        float m  = s * (1.0f/CAT);
        float rr = rsqrtf(s2 * (1.0f/CAT) - m*m + 1e-5f);
        if (l == 0){ rowm[row] = m; rowr[row] = rr; }
        #pragma unroll
        for (int ch=0; ch<5; ++ch){
            acc[ch].x += rr*e[ch].x; acc[ch].y += rr*e[ch].y;
            acc[ch].z += rr*e[ch].z; acc[ch].w += rr*e[ch].w;
        }
        mracc += rr*m;
    }
    __shared__ float part[4][CAT];
    __shared__ float pm[4];
    #pragma unroll
    for (int ch=0; ch<4; ++ch) *(float4*)&part[w][ch*256 + l*4] = acc[ch];
    *(float4*)&part[w][IN_ + l*4] = acc[4];
    if (l == 0) pm[w] = mracc;
    __syncthreads();
    float* ap = Apart + ((size_t)b*4 + qq)*APLD;
    for (int c = t; c < 1280; c += 256)
        ap[c] = part[0][c] + part[1][c] + part[2][c] + part[3][c];
    if (t == 0) ap[1280] = pm[0] + pm[1] + pm[2] + pm[3];
}

__global__ __launch_bounds__(256)
void abar_reduce(const float* __restrict__ Apart, float* __restrict__ Abar,
                 float* __restrict__ mbar)
{
    const int b = blockIdx.x, t = threadIdx.x;
    const float* ap = Apart + (size_t)b*4*APLD;
    for (int c = t; c < 1281; c += 256){
        float s = ap[c] + ap[APLD + c] + ap[2*APLD + c] + ap[3*APLD + c];
        if (c < 1280) Abar[(size_t)b*CAT + c] = s * (1.f/N_);
        else mbar[b] = s * (1.f/N_);
    }
}

// ---------- pooled[b,d] = Abar[b]·Wfs[d] - mbar[b]*wsum[d] + bfs[d]  (f32) ----------
__global__ __launch_bounds__(256)
void pooled_kernel(const float* __restrict__ Abar, const float* __restrict__ mbar,
                   const float* __restrict__ Wfs, const float* __restrict__ wsum,
                   const float* __restrict__ bfs, float* __restrict__ pooled)
{
    const int b = blockIdx.x, d = threadIdx.x;
    __shared__ float ab[CAT];
    for (int c=d;c<CAT;c+=256) ab[c] = Abar[(size_t)b*CAT + c];
    __syncthreads();
    const float* w = Wfs + (size_t)d*CAT;
    float s = 0.f;
    for (int c=0;c<CAT;c+=4){
        float4 wv = *(const float4*)(w+c);
        s += ab[c]*wv.x + ab[c+1]*wv.y + ab[c+2]*wv.z + ab[c+3]*wv.w;
    }
    pooled[b*D_ + d] = s - mbar[b]*wsum[d] + bfs[d];
}

// ---------- mean over tokens ----------
__global__ __launch_bounds__(256)
void mean_tokens(const float* __restrict__ src, float* __restrict__ dst)
{
    int b = blockIdx.x, d = threadIdx.x;
    const float* p = src + (size_t)b*N_*D_ + d;
    float s = 0.f;
    for (int n=0;n<N_;++n) s += p[(size_t)n*D_];
    dst[b*D_ + d] = s * (1.0f/N_);
}

// ---------- parent logits + routing ----------
__global__ __launch_bounds__(256)
void parent_kernel(const float* __restrict__ pooled, const float* __restrict__ Wpc,
                   const float* __restrict__ bpc, float* __restrict__ out, int* __restrict__ yhat)
{
    const int b = blockIdx.x, t = threadIdx.x;
    __shared__ __align__(16) float pl[D_];
    __shared__ float lg[NC_];
    pl[t] = pooled[b*D_ + t];
    __syncthreads();
    for (int c = t; c < NC_; c += 256){
        const float4* w4 = (const float4*)(Wpc + (size_t)c*D_);
        float s = 0.f;
        #pragma unroll 16
        for (int j=0;j<64;++j){
            float4 wv = w4[j];
            s += pl[j*4]*wv.x + pl[j*4+1]*wv.y + pl[j*4+2]*wv.z + pl[j*4+3]*wv.w;
        }
        lg[c] = s + bpc[c];
    }
    __syncthreads();
    float s=0.f, s2=0.f, bmv=-3.4e38f; int bidx=0;
    for (int c=t;c<NC_;c+=256){
        float x = lg[c]; s += x; s2 += x*x;
        if (x > bmv){ bmv=x; bidx=c; }
    }
    #pragma unroll
    for (int off=32; off>0; off>>=1){
        s  += __shfl_down(s, off);
        s2 += __shfl_down(s2, off);
        float ov = __shfl_down(bmv, off); int oi = __shfl_down(bidx, off);
        if (ov > bmv || (ov == bmv && oi < bidx)){ bmv=ov; bidx=oi; }
    }
    __shared__ float rs[4], rs2[4], rmv[4]; __shared__ int ri[4];
    __shared__ float fm, fr_;
    int w = t >> 6;
    if ((t & 63) == 0){ rs[w]=s; rs2[w]=s2; rmv[w]=bmv; ri[w]=bidx; }
    __syncthreads();
    if (t == 0){
        float S=0.f, S2=0.f, mv=-3.4e38f; int mi=0;
        for (int i=0;i<4;++i){
            S += rs[i]; S2 += rs2[i];
            if (rmv[i] > mv || (rmv[i] == mv && ri[i] < mi)){ mv=rmv[i]; mi=ri[i]; }
        }
        float mean = S*(1.0f/NC_);
        float var  = S2*(1.0f/NC_) - mean*mean;
        fm = mean; fr_ = rsqrtf(var + 1e-5f);
        yhat[b] = mi;
    }
    __syncthreads();
    for (int c=t;c<NC_;c+=256) out[(size_t)b*NC_ + c] = (lg[c]-fm)*fr_;
}

// ---------- routed child classifiers ----------
__global__ __launch_bounds__(64)
void child_kernel(const float* __restrict__ sp, const int* __restrict__ yhat,
                  const float* __restrict__ Wc0, const float* __restrict__ bc0,
                  const float* __restrict__ Wc1, const float* __restrict__ bc1,
                  float* __restrict__ out_c0, float* __restrict__ out_c1)
{
    const int b = blockIdx.x, t = threadIdx.x;
    __shared__ float spl[D_];
    for (int i=t;i<D_;i+=64) spl[i] = sp[b*D_ + i];
    __syncthreads();
    const int y = yhat[b];
    __shared__ float c0v[S0_], c1v[S1_];
    if (t < S0_){
        const float* w = Wc0 + (size_t)y*D_*S0_ + t;
        float s = 0.f;
        for (int d=0;d<D_;++d) s += spl[d]*w[(size_t)d*S0_];
        c0v[t] = s + bc0[y*S0_ + t];
    } else if (t < S0_+S1_){
        int k = t - S0_;
        const float* w = Wc1 + (size_t)y*D_*S1_ + k;
        float s = 0.f;
        for (int d=0;d<D_;++d) s += spl[d]*w[(size_t)d*S1_];
        c1v[k] = s + bc1[y*S1_ + k];
    }
    __syncthreads();
    __shared__ float st[4];
    if (t == 0){
        float m=0.f; for (int i=0;i<S0_;++i) m += c0v[i]; m *= (1.0f/S0_);
        float v=0.f; for (int i=0;i<S0_;++i){ float d=c0v[i]-m; v += d*d; } v *= (1.0f/S0_);
        st[0]=m; st[1]=rsqrtf(v+1e-5f);
        m=0.f; for (int i=0;i<S1_;++i) m += c1v[i]; m *= (1.0f/S1_);
        v=0.f; for (int i=0;i<S1_;++i){ float d=c1v[i]-m; v += d*d; } v *= (1.0f/S1_);
        st[2]=m; st[3]=rsqrtf(v+1e-5f);
    }
    __syncthreads();
    if (t < S0_) out_c0[b*S0_ + t] = (c0v[t]-st[0])*st[1];
    else if (t < S0_+S1_) out_c1[b*S1_ + (t-S0_)] = (c1v[t-S0_]-st[2])*st[3];
}

extern "C" void kernel_launch(void* const* d_in, const int* in_sizes, int n_in,
                              void* d_out, int out_size, void* d_ws, size_t ws_size,
                              hipStream_t stream)
{
    const float* h   = (const float*)d_in[0];
    const float* Wp  = (const float*)d_in[1];
    const float* bp  = (const float*)d_in[2];
    const float* Wsub= (const float*)d_in[3];
    const float* bs  = (const float*)d_in[4];
    const float* Wq  = (const float*)d_in[5];
    const float* bq  = (const float*)d_in[6];
    const float* Wk  = (const float*)d_in[7];
    const float* bk  = (const float*)d_in[8];
    const float* Wv  = (const float*)d_in[9];
    const float* bv  = (const float*)d_in[10];
    const float* Wo  = (const float*)d_in[11];
    const float* bo  = (const float*)d_in[12];
    const float* Wfs = (const float*)d_in[13];
    const float* bfs = (const float*)d_in[14];
    const float* Wpc = (const float*)d_in[15];
    const float* bpc = (const float*)d_in[16];
    const float* Wc0 = (const float*)d_in[17];
    const float* bc0 = (const float*)d_in[18];
    const float* Wc1 = (const float*)d_in[19];
    const float* bc1 = (const float*)d_in[20];

    float* out = (float*)d_out;
    float* out_pl = out;                         // [256,1000]
    float* out_c0 = out + 256000;                // [256,10]
    float* out_c1 = out + 258560;                // [256,20]
    float* out_fs = out + 263680;                // [256,196,256]
    float* out_se = out + 13108736;              // [256,196,256]

    // ---- workspace: 8 bf16 units (slots 0-3 = hb, 4-7 time-shared) ----
    ushort_t* U = (ushort_t*)d_ws;
    const size_t UN = (size_t)ROWS * D_;         // 12,845,056
    ushort_t* hb   = U + 0*UN;                   // bf16(h), spans 4 UN
    ushort_t* s4   = U + 4*UN;                   // pe
    ushort_t* s5   = U + 5*UN;                   // se (K and V for attn)
    ushort_t* s6   = U + 6*UN;                   // q'' -> integ
    ushort_t* s7   = U + 7*UN;                   // ao'

    float* fmisc = (float*)(U + 8*UN);
    float* rowm = fmisc;                          // 50176
    float* rowr = rowm + ROWS;                    // 50176
    float* wsmb = rowr + ROWS;                    // 256
    float* pooled = wsmb + D_;                    // 65536
    float* sp   = pooled + (size_t)B_*D_;         // 65536
    float* mbar = sp + (size_t)B_*D_;             // 256
    float* bqk  = mbar + 256;                     // 256
    float* bvo  = bqk + 256;                      // 256
    float* Abar = bvo + 256;                      // 327680
    float* Apart = Abar + (size_t)B_*CAT;         // 256*4*1344
    int*   yhat = (int*)(Apart + (size_t)B_*4*APLD);
    ushort_t* wp = (ushort_t*)(yhat + 512);
    ushort_t* WpsH = wp;               // [512][1024]
    ushort_t* WfsH = WpsH + 524288;    // [256][1280]
    ushort_t* WqkH = WfsH + 327680;    // [256][256]
    ushort_t* WvoH = WqkH + 65536;     // [256][256]

    // convert h + fused weight prep + folded attn weights
    cvt8_kernel<<<25088, 256, 0, stream>>>(h, hb);
    prep_kernel<<<3392, 256, 0, stream>>>(Wp, Wsub, Wfs, WpsH, WfsH, wsmb);
    wqk_kernel<<<256, 256, 0, stream>>>(Wq, Wk, bq, WqkH, bqk);
    wvo_kernel<<<256, 256, 0, stream>>>(Wo, Wv, bv, bo, WvoH, bvo);

    // fused pe+se -> pe s4, se f32 out_se + bf16 s5   (grid 784)
    gemm_bf<32,32,2,7><<<784, 512, 0, stream>>>(
        hb, hb, IN_, IN_, WpsH, IN_, bp, bs,
        out_se, s4, s5, nullptr, nullptr, nullptr);
    // q'' = pe @ Wqk^T + bqk (scale folded; k never computed) -> s6   (grid 392)
    gemm_bf<8,8,1,3><<<392, 512, 0, stream>>>(
        s4, s4, D_, D_, WqkH, D_, bqk, nullptr,
        nullptr, s6, nullptr, nullptr, nullptr, nullptr);
    // attention with K = V = se  -> ao' s7
    attn_mfma<<<dim3(B_, H_), 256, 0, stream>>>(s6, s5, s5, s7);
    // integ = ao' @ Wvo^T + bvo (v never computed) -> bf16 s6   (grid 392)
    gemm_bf<8,8,1,3><<<392, 512, 0, stream>>>(
        s7, s7, D_, D_, WvoH, D_, bvo, nullptr,
        nullptr, s6, nullptr, nullptr, nullptr, nullptr);
    // fused LN stats + abar partial (f32 h + bf16 integ)
    abar_part<<<dim3(B_,4), 256, 0, stream>>>(h, s6, rowm, rowr, Apart);
    // fs (A = hb | integ bf16; LN folded) -> out_fs   (grid 392)
    gemm_bf<40,32,1,5><<<392, 512, 0, stream>>>(
        hb, s6, IN_, D_, WfsH, CAT, bfs, nullptr,
        out_fs, nullptr, nullptr, rowm, rowr, wsmb);
    // exact pooled via Abar identity
    abar_reduce<<<B_, 256, 0, stream>>>(Apart, Abar, mbar);
    pooled_kernel<<<B_, 256, 0, stream>>>(Abar, mbar, Wfs, wsmb, bfs, pooled);
    // sp from se
    mean_tokens<<<B_, 256, 0, stream>>>(out_se, sp);
    // parent logits + routing
    parent_kernel<<<B_, 256, 0, stream>>>(pooled, Wpc, bpc, out_pl, yhat);
    // routed child classifiers
    child_kernel<<<B_, 64, 0, stream>>>(sp, yhat, Wc0, bc0, Wc1, bc1, out_c0, out_c1);
}

// Round 15
// 454.726 us; speedup vs baseline: 1.1864x; 1.1864x over previous
//
#include <hip/hip_runtime.h>
#include <hip/hip_bf16.h>
#include <math.h>

// Problem dims
#define B_   256
#define N_   196
#define IN_  1024
#define D_   256
#define H_   8
#define HD_  32
#define NC_  1000
#define S0_  10
#define S1_  20
#define ROWS (B_*N_)      // 50176
#define CAT  (IN_+D_)     // 1280

typedef unsigned short ushort_t;
typedef short bf16x8 __attribute__((ext_vector_type(8)));
typedef float f32x4  __attribute__((ext_vector_type(4)));
typedef ushort_t us4 __attribute__((ext_vector_type(4)));
typedef ushort_t us8 __attribute__((ext_vector_type(8)));

__device__ __forceinline__ ushort_t f2bf(float f){
    __hip_bfloat16 b = __float2bfloat16(f);
    ushort_t u; __builtin_memcpy(&u, &b, 2); return u;
}
__device__ __forceinline__ float bf2f(ushort_t h){
    union { unsigned int u; float f; } x; x.u = ((unsigned int)h) << 16;
    return x.f;
}
__device__ __forceinline__ float gelu_tanh(float x){
    float x3 = x*x*x;
    float inner = 0.7978845608028654f*(x + 0.044715f*x3);
    return 0.5f*x*(1.0f + tanhf(inner));
}

// ---------- async global->LDS, 16B per lane ----------
typedef __attribute__((address_space(1))) const unsigned int gu32;
typedef __attribute__((address_space(3))) unsigned int lu32;
__device__ __forceinline__ void gload_lds16b(const void* g, void* l){
    __builtin_amdgcn_global_load_lds((gu32*)g, (lu32*)l, 16, 0, 0);
}
// swizzle (refcheck'd r4-r14): LDS(row, slot') holds global (row, slot' ^ ((row>>1)&3));
// slots are 16B units; frag read XORs back.
__device__ __forceinline__ bf16x8 frag32(const ushort_t* lds, int row, int fq){
    return *(const bf16x8*)&lds[row*32 + ((fq ^ ((row >> 1) & 3)) << 3)];
}

// ---------- f32 -> bf16 convert for h (8 elems/thread) ----------
__global__ __launch_bounds__(256)
void cvt8_kernel(const float* __restrict__ src, ushort_t* __restrict__ dst)
{
    size_t i = ((size_t)blockIdx.x*256 + threadIdx.x)*8;
    float4 a = *(const float4*)(src + i);
    float4 b = *(const float4*)(src + i + 4);
    us8 o;
    o[0]=f2bf(a.x); o[1]=f2bf(a.y); o[2]=f2bf(a.z); o[3]=f2bf(a.w);
    o[4]=f2bf(b.x); o[5]=f2bf(b.y); o[6]=f2bf(b.z); o[7]=f2bf(b.w);
    *(us8*)(dst + i) = o;
}

// ---------- fused weight prep: converts + colsum(Wfs) + folded Wqk/Wvo; grid 3904 ----------
__global__ __launch_bounds__(256)
void prep_kernel(const float* __restrict__ Wp, const float* __restrict__ Wsub,
                 const float* __restrict__ Wfs,
                 const float* __restrict__ Wq, const float* __restrict__ Wk,
                 const float* __restrict__ bq,
                 const float* __restrict__ Wo, const float* __restrict__ Wv,
                 const float* __restrict__ bv, const float* __restrict__ bo,
                 ushort_t* __restrict__ WpsH, ushort_t* __restrict__ WfsH,
                 ushort_t* __restrict__ WqkH, ushort_t* __restrict__ WvoH,
                 float* __restrict__ wsum, float* __restrict__ bqk,
                 float* __restrict__ bvo)
{
    const int b = blockIdx.x, t = threadIdx.x;
    if (b < 1024){ int i=b*256+t; WpsH[i] = f2bf(Wp[i]); }
    else if (b < 2048){ int i=(b-1024)*256+t; WpsH[262144+i] = f2bf(Wsub[i]); }
    else if (b < 3328){ int i=(b-2048)*256+t; WfsH[i] = f2bf(Wfs[i]); }
    else if (b < 3392){
        int d = (b-3328)*4 + (t>>6), l = t & 63;
        const float* w = Wfs + (size_t)d*CAT;
        float s = 0.f;
        #pragma unroll
        for (int c0=0;c0<CAT;c0+=256){
            float4 v = *(const float4*)(w + c0 + l*4);
            s += v.x+v.y+v.z+v.w;
        }
        #pragma unroll
        for (int off=32;off>0;off>>=1) s += __shfl_down(s, off);
        if (l == 0) wsum[d] = s;
    }
    else if (b < 3648){
        // Wqk[c][d] = s*Σ_e Wq[e][d]·Wk[e][c];  bqk[c] = s*Σ_e bq[e]·Wk[e][c]
        const int c = b - 3392, d = t;
        const float sc = 0.17677669529663687f;
        float acc = 0.f, accb = 0.f;
        for (int e = 0; e < 256; ++e){
            float wkc = Wk[e*256 + c];
            acc  += Wq[e*256 + d] * wkc;
            accb += bq[e] * wkc;
        }
        WqkH[c*256 + d] = f2bf(acc * sc);
        if (d == 0) bqk[c] = accb * sc;
    }
    else {
        // Wvo[e2][c] = Σ_e Wo[e2][e]·Wv[e][c];  bvo[e2] = Wo[e2]·bv + bo[e2]
        const int e2 = b - 3648, c = t;
        float acc = 0.f, accb = 0.f;
        for (int e = 0; e < 256; ++e){
            float woe = Wo[e2*256 + e];
            acc  += woe * Wv[e*256 + c];
            accb += woe * bv[e];
        }
        WvoH[e2*256 + c] = f2bf(acc);
        if (c == 0) bvo[e2] = accb + bo[e2];
    }
}

// ---------- 3-deep counted-vmcnt pipelined bf16 GEMM (addr-hoisted + setprio) ----------
// 128x256 tile, 8 waves (2x4), BK=32, 3 LDS buffers (72KB).
// EPI: 7=pese(gelu; col<256->pe o1h, else seF f32o + se o2h)
//      3=plain bf16(o1h)  5=fs(LN-fold->f32o)
template<int KCH, int KCH1, int NBN, int EPI>
__global__ __launch_bounds__(512, 4)
void gemm_bf(const ushort_t* __restrict__ A1b, const ushort_t* __restrict__ A2b,
             int lda1, int lda2,
             const ushort_t* __restrict__ BH, int ldb,
             const float* __restrict__ bias1, const float* __restrict__ bias2,
             float* __restrict__ f32o, ushort_t* __restrict__ o1h, ushort_t* __restrict__ o2h,
             const float* __restrict__ rowm, const float* __restrict__ rowr,
             const float* __restrict__ wsump)
{
    __shared__ ushort_t SA[3][128*32];   // 3 x 8 KB
    __shared__ ushort_t SB[3][256*32];   // 3 x 16 KB
    const int nwg = gridDim.x, cpx = nwg >> 3, bid = blockIdx.x;
    const int wg = (bid & 7)*cpx + (bid >> 3);
    const int bn = (wg % NBN)*256, bm = (wg / NBN)*128;
    const int t = threadIdx.x, lane = t & 63, wid = t >> 6;
    const int wr = wid >> 2, wc = wid & 3, fr = lane & 15, fq = lane >> 4;

    // hoisted per-lane staging pointers; advance 64B (=32 ushorts) per staged chunk
    const int rr = lane >> 2;
    const int sl = (lane & 3) ^ ((lane >> 3) & 3);
    const ushort_t* srcA  = A1b + (size_t)(bm + wid*16 + rr)*lda1 + sl*8;
    const ushort_t* srcB0 = BH  + (size_t)(bn + wid*32 + rr)*ldb  + sl*8;
    const ushort_t* srcB1 = srcB0 + (size_t)16*ldb;

    f32x4 acc[4][4];
    #pragma unroll
    for (int i=0;i<4;++i)
        #pragma unroll
        for (int j=0;j<4;++j) acc[i][j] = (f32x4){0.f,0.f,0.f,0.f};

    auto stageT = [&](int buf, int kc){     // 3 vmem instrs per wave
        if (KCH1 < KCH && kc == KCH1)
            srcA = A2b + (size_t)(bm + wid*16 + rr)*lda2 + sl*8;
        gload_lds16b(srcA,  &SA[buf][wid*512]);
        gload_lds16b(srcB0, &SB[buf][wid*1024]);
        gload_lds16b(srcB1, &SB[buf][wid*1024 + 512]);
        srcA += 32; srcB0 += 32; srcB1 += 32;
    };
    auto compute = [&](int buf){
        bf16x8 a[4], b[4];
        #pragma unroll
        for (int i=0;i<4;++i){
            a[i] = frag32(SA[buf], wr*64 + i*16 + fr, fq);
            b[i] = frag32(SB[buf], wc*64 + i*16 + fr, fq);
        }
        __builtin_amdgcn_s_setprio(1);
        #pragma unroll
        for (int i=0;i<4;++i)
            #pragma unroll
            for (int j=0;j<4;++j)
                acc[i][j] = __builtin_amdgcn_mfma_f32_16x16x32_bf16(a[i], b[j], acc[i][j], 0,0,0);
        __builtin_amdgcn_s_setprio(0);
    };

    // prologue: 3 tiles in flight; wait only tile 0
    stageT(0, 0);
    stageT(1, 1);
    stageT(2, 2);
    asm volatile("s_waitcnt vmcnt(6)" ::: "memory");
    __builtin_amdgcn_sched_barrier(0);
    __builtin_amdgcn_s_barrier();

    int cur = 0;
    for (int kc = 0; kc < KCH; ++kc){
        compute(cur);
        if (kc + 1 >= KCH) break;
        asm volatile("s_waitcnt lgkmcnt(0)" ::: "memory");   // this wave's ds_reads retired
        __builtin_amdgcn_s_barrier();                        // all waves done reading buf cur
        if (kc + 3 < KCH){
            stageT(cur, kc + 3);                             // refill freed buffer
            asm volatile("s_waitcnt vmcnt(6)" ::: "memory"); // wait tile kc+1 only
        } else if (kc + 2 < KCH){
            asm volatile("s_waitcnt vmcnt(3)" ::: "memory");
        } else {
            asm volatile("s_waitcnt vmcnt(0)" ::: "memory");
        }
        __builtin_amdgcn_sched_barrier(0);
        __builtin_amdgcn_s_barrier();                        // tile kc+1 visible to all
        cur = (cur == 2) ? 0 : cur + 1;
    }

    // epilogue
    #pragma unroll
    for (int i=0;i<4;++i){
        #pragma unroll
        for (int j=0;j<4;++j){
            const int col = bn + wc*64 + j*16 + fr;
            #pragma unroll
            for (int r=0;r<4;++r){
                const int row = bm + wr*64 + i*16 + fq*4 + r;
                float x = acc[i][j][r];
                if (EPI == 7){
                    if (col < 256){
                        float y = gelu_tanh(x + bias1[col]);
                        o1h[(size_t)row*D_ + col] = f2bf(y);
                    } else {
                        float y = gelu_tanh(x + bias2[col-256]);
                        f32o[(size_t)row*D_ + (col-256)] = y;
                        o2h[(size_t)row*D_ + (col-256)] = f2bf(y);
                    }
                } else if (EPI == 3){
                    o1h[(size_t)row*D_ + col] = f2bf(x + bias1[col]);
                } else { // EPI == 5
                    f32o[(size_t)row*D_ + col] = rowr[row]*(x - rowm[row]*wsump[col]) + bias1[col];
                }
            }
        }
    }
}

// ---------- MFMA attention (bf16 in, bf16 out); K and V are both se ----------
#define KROWS 208
#define KLD   40
#define VLD   232

__global__ __launch_bounds__(256)
void attn_mfma(const ushort_t* __restrict__ qhi,
               const ushort_t* __restrict__ khi,
               const ushort_t* __restrict__ vhi,
               ushort_t* __restrict__ aohi)
{
    __shared__ ushort_t Khi[KROWS*KLD];
    __shared__ ushort_t Vthi[32*VLD];

    const int b = blockIdx.x, hh = blockIdx.y;
    const int t = threadIdx.x;
    const int lane = t & 63;
    const int wid  = t >> 6;
    const int fr = lane & 15;
    const int fq = lane >> 4;
    const size_t bbase = (size_t)b*N_*D_ + hh*HD_;

    for (int idx = t; idx < KROWS*4; idx += 256){
        int row = idx >> 2, c8 = (idx & 3) << 3;
        us8 vh;
        if (row < N_){
            vh = *(const us8*)(khi + bbase + (size_t)row*D_ + c8);
        } else {
            #pragma unroll
            for (int j=0;j<8;++j) vh[j]=0;
        }
        *(us8*)&Khi[row*KLD + c8] = vh;
    }
    for (int idx = t; idx < 224*4; idx += 256){
        int key = idx >> 2, c8 = (idx & 3) << 3;
        us8 vh;
        if (key < N_){
            vh = *(const us8*)(vhi + bbase + (size_t)key*D_ + c8);
        } else {
            #pragma unroll
            for (int j=0;j<8;++j) vh[j]=0;
        }
        int w = key & 31, cc = key >> 5;
        int slot;
        if (w < 16) slot = cc*32 + (w>>2)*8 + (w&3);
        else { int w2 = w-16; slot = cc*32 + (w2>>2)*8 + 4 + (w2&3); }
        #pragma unroll
        for (int j=0;j<8;++j)
            Vthi[(c8 + j)*VLD + slot] = vh[j];
    }
    __syncthreads();

    for (int qt = wid; qt < 13; qt += 4){
        int qrow = qt*16 + fr; if (qrow > N_-1) qrow = N_-1;
        const bf16x8 qh = *(const bf16x8*)(qhi + bbase + (size_t)qrow*D_ + fq*8);

        f32x4 s[13];
        #pragma unroll
        for (int kt=0; kt<13; ++kt) s[kt] = (f32x4){0.f,0.f,0.f,0.f};
        #pragma unroll
        for (int kt=0; kt<13; ++kt){
            const bf16x8 kh = *(const bf16x8*)&Khi[(kt*16 + fr)*KLD + fq*8];
            s[kt] = __builtin_amdgcn_mfma_f32_16x16x32_bf16(kh, qh, s[kt], 0,0,0);
        }
        if (fq > 0) s[12] = (f32x4){-1e30f,-1e30f,-1e30f,-1e30f};

        float m = -3.4e38f;
        #pragma unroll
        for (int kt=0; kt<13; ++kt)
            #pragma unroll
            for (int r=0;r<4;++r) m = fmaxf(m, s[kt][r]);
        m = fmaxf(m, __shfl_xor(m, 16));
        m = fmaxf(m, __shfl_xor(m, 32));
        float sum = 0.f;
        #pragma unroll
        for (int kt=0; kt<13; ++kt)
            #pragma unroll
            for (int r=0;r<4;++r){
                float p = __expf(s[kt][r] - m);
                s[kt][r] = p; sum += p;
            }
        sum += __shfl_xor(sum, 16);
        sum += __shfl_xor(sum, 32);
        const float inv = 1.0f / sum;

        f32x4 o0 = (f32x4){0.f,0.f,0.f,0.f};
        f32x4 o1 = (f32x4){0.f,0.f,0.f,0.f};
        #pragma unroll
        for (int c=0;c<7;++c){
            bf16x8 ph;
            #pragma unroll
            for (int r=0;r<4;++r){
                ph[r]   = (short)f2bf(s[2*c][r]);
                ph[4+r] = (short)((c < 6) ? f2bf(s[2*c+1][r]) : 0);
            }
            const int coff = c*32 + fq*8;
            const bf16x8 v0h = *(const bf16x8*)&Vthi[(fr)*VLD + coff];
            const bf16x8 v1h = *(const bf16x8*)&Vthi[(16+fr)*VLD + coff];
            o0 = __builtin_amdgcn_mfma_f32_16x16x32_bf16(v0h, ph, o0, 0,0,0);
            o1 = __builtin_amdgcn_mfma_f32_16x16x32_bf16(v1h, ph, o1, 0,0,0);
        }
        int tok = qt*16 + fr;
        if (tok < N_){
            const size_t obase = bbase + (size_t)tok*D_;
            #pragma unroll
            for (int r=0;r<4;++r){
                aohi[obase + fq*4 + r]      = f2bf(o0[r]*inv);
                aohi[obase + 16 + fq*4 + r] = f2bf(o1[r]*inv);
            }
        }
    }
}

// ---------- fused rowstats + abar partial, wave-per-row (bf16 h + bf16 integ) ----------
#define APLD 1344
__global__ __launch_bounds__(256)
void abar_part(const ushort_t* __restrict__ hb, const ushort_t* __restrict__ integb,
               float* __restrict__ rowm, float* __restrict__ rowr,
               float* __restrict__ Apart)
{
    const int b = blockIdx.x, qq = blockIdx.y, t = threadIdx.x;
    const int l = t & 63, w = t >> 6;
    const int n0 = qq*49;
    float4 acc[5];
    #pragma unroll
    for (int ch=0; ch<5; ++ch) acc[ch] = (float4){0.f,0.f,0.f,0.f};
    float mracc = 0.f;
    for (int n = w; n < 49; n += 4){
        const int row = b*N_ + n0 + n;
        const ushort_t* hr = hb + (size_t)row*IN_;
        float4 e[5];
        #pragma unroll
        for (int ch=0; ch<4; ++ch){
            us4 iv = *(const us4*)(hr + ch*256 + l*4);
            e[ch].x = bf2f(iv[0]); e[ch].y = bf2f(iv[1]);
            e[ch].z = bf2f(iv[2]); e[ch].w = bf2f(iv[3]);
        }
        {
            us4 iv = *(const us4*)(integb + (size_t)row*D_ + l*4);
            e[4].x = bf2f(iv[0]); e[4].y = bf2f(iv[1]);
            e[4].z = bf2f(iv[2]); e[4].w = bf2f(iv[3]);
        }
        float s = 0.f, s2 = 0.f;
        #pragma unroll
        for (int ch=0; ch<5; ++ch){
            s  += e[ch].x + e[ch].y + e[ch].z + e[ch].w;
            s2 += e[ch].x*e[ch].x + e[ch].y*e[ch].y + e[ch].z*e[ch].z + e[ch].w*e[ch].w;
        }
        #pragma unroll
        for (int off=32; off>0; off>>=1){ s += __shfl_xor(s, off); s2 += __shfl_xor(s2, off); }
        float m  = s * (1.0f/CAT);
        float rr = rsqrtf(s2 * (1.0f/CAT) - m*m + 1e-5f);
        if (l == 0){ rowm[row] = m; rowr[row] = rr; }
        #pragma unroll
        for (int ch=0; ch<5; ++ch){
            acc[ch].x += rr*e[ch].x; acc[ch].y += rr*e[ch].y;
            acc[ch].z += rr*e[ch].z; acc[ch].w += rr*e[ch].w;
        }
        mracc += rr*m;
    }
    __shared__ float part[4][CAT];
    __shared__ float pm[4];
    #pragma unroll
    for (int ch=0; ch<4; ++ch) *(float4*)&part[w][ch*256 + l*4] = acc[ch];
    *(float4*)&part[w][IN_ + l*4] = acc[4];
    if (l == 0) pm[w] = mracc;
    __syncthreads();
    float* ap = Apart + ((size_t)b*4 + qq)*APLD;
    for (int c = t; c < 1280; c += 256)
        ap[c] = part[0][c] + part[1][c] + part[2][c] + part[3][c];
    if (t == 0) ap[1280] = pm[0] + pm[1] + pm[2] + pm[3];
}

__global__ __launch_bounds__(256)
void abar_reduce(const float* __restrict__ Apart, float* __restrict__ Abar,
                 float* __restrict__ mbar)
{
    const int b = blockIdx.x, t = threadIdx.x;
    const float* ap = Apart + (size_t)b*4*APLD;
    for (int c = t; c < 1281; c += 256){
        float s = ap[c] + ap[APLD + c] + ap[2*APLD + c] + ap[3*APLD + c];
        if (c < 1280) Abar[(size_t)b*CAT + c] = s * (1.f/N_);
        else mbar[b] = s * (1.f/N_);
    }
}

// ---------- pooled[b,d] = Abar[b]·Wfs[d] - mbar[b]*wsum[d] + bfs[d]  (f32) ----------
__global__ __launch_bounds__(256)
void pooled_kernel(const float* __restrict__ Abar, const float* __restrict__ mbar,
                   const float* __restrict__ Wfs, const float* __restrict__ wsum,
                   const float* __restrict__ bfs, float* __restrict__ pooled)
{
    const int b = blockIdx.x, d = threadIdx.x;
    __shared__ float ab[CAT];
    for (int c=d;c<CAT;c+=256) ab[c] = Abar[(size_t)b*CAT + c];
    __syncthreads();
    const float* w = Wfs + (size_t)d*CAT;
    float s = 0.f;
    for (int c=0;c<CAT;c+=4){
        float4 wv = *(const float4*)(w+c);
        s += ab[c]*wv.x + ab[c+1]*wv.y + ab[c+2]*wv.z + ab[c+3]*wv.w;
    }
    pooled[b*D_ + d] = s - mbar[b]*wsum[d] + bfs[d];
}

// ---------- mean over tokens (bf16 src) ----------
__global__ __launch_bounds__(256)
void mean_tokens_bf(const ushort_t* __restrict__ src, float* __restrict__ dst)
{
    int b = blockIdx.x, d = threadIdx.x;
    const ushort_t* p = src + (size_t)b*N_*D_ + d;
    float s = 0.f;
    for (int n=0;n<N_;++n) s += bf2f(p[(size_t)n*D_]);
    dst[b*D_ + d] = s * (1.0f/N_);
}

// ---------- parent logits + routing ----------
__global__ __launch_bounds__(256)
void parent_kernel(const float* __restrict__ pooled, const float* __restrict__ Wpc,
                   const float* __restrict__ bpc, float* __restrict__ out, int* __restrict__ yhat)
{
    const int b = blockIdx.x, t = threadIdx.x;
    __shared__ __align__(16) float pl[D_];
    __shared__ float lg[NC_];
    pl[t] = pooled[b*D_ + t];
    __syncthreads();
    for (int c = t; c < NC_; c += 256){
        const float4* w4 = (const float4*)(Wpc + (size_t)c*D_);
        float s = 0.f;
        #pragma unroll 16
        for (int j=0;j<64;++j){
            float4 wv = w4[j];
            s += pl[j*4]*wv.x + pl[j*4+1]*wv.y + pl[j*4+2]*wv.z + pl[j*4+3]*wv.w;
        }
        lg[c] = s + bpc[c];
    }
    __syncthreads();
    float s=0.f, s2=0.f, bmv=-3.4e38f; int bidx=0;
    for (int c=t;c<NC_;c+=256){
        float x = lg[c]; s += x; s2 += x*x;
        if (x > bmv){ bmv=x; bidx=c; }
    }
    #pragma unroll
    for (int off=32; off>0; off>>=1){
        s  += __shfl_down(s, off);
        s2 += __shfl_down(s2, off);
        float ov = __shfl_down(bmv, off); int oi = __shfl_down(bidx, off);
        if (ov > bmv || (ov == bmv && oi < bidx)){ bmv=ov; bidx=oi; }
    }
    __shared__ float rs[4], rs2[4], rmv[4]; __shared__ int ri[4];
    __shared__ float fm, fr_;
    int w = t >> 6;
    if ((t & 63) == 0){ rs[w]=s; rs2[w]=s2; rmv[w]=bmv; ri[w]=bidx; }
    __syncthreads();
    if (t == 0){
        float S=0.f, S2=0.f, mv=-3.4e38f; int mi=0;
        for (int i=0;i<4;++i){
            S += rs[i]; S2 += rs2[i];
            if (rmv[i] > mv || (rmv[i] == mv && ri[i] < mi)){ mv=rmv[i]; mi=ri[i]; }
        }
        float mean = S*(1.0f/NC_);
        float var  = S2*(1.0f/NC_) - mean*mean;
        fm = mean; fr_ = rsqrtf(var + 1e-5f);
        yhat[b] = mi;
    }
    __syncthreads();
    for (int c=t;c<NC_;c+=256) out[(size_t)b*NC_ + c] = (lg[c]-fm)*fr_;
}

// ---------- routed child classifiers ----------
__global__ __launch_bounds__(64)
void child_kernel(const float* __restrict__ sp, const int* __restrict__ yhat,
                  const float* __restrict__ Wc0, const float* __restrict__ bc0,
                  const float* __restrict__ Wc1, const float* __restrict__ bc1,
                  float* __restrict__ out_c0, float* __restrict__ out_c1)
{
    const int b = blockIdx.x, t = threadIdx.x;
    __shared__ float spl[D_];
    for (int i=t;i<D_;i+=64) spl[i] = sp[b*D_ + i];
    __syncthreads();
    const int y = yhat[b];
    __shared__ float c0v[S0_], c1v[S1_];
    if (t < S0_){
        const float* w = Wc0 + (size_t)y*D_*S0_ + t;
        float s = 0.f;
        for (int d=0;d<D_;++d) s += spl[d]*w[(size_t)d*S0_];
        c0v[t] = s + bc0[y*S0_ + t];
    } else if (t < S0_+S1_){
        int k = t - S0_;
        const float* w = Wc1 + (size_t)y*D_*S1_ + k;
        float s = 0.f;
        for (int d=0;d<D_;++d) s += spl[d]*w[(size_t)d*S1_];
        c1v[k] = s + bc1[y*S1_ + k];
    }
    __syncthreads();
    __shared__ float st[4];
    if (t == 0){
        float m=0.f; for (int i=0;i<S0_;++i) m += c0v[i]; m *= (1.0f/S0_);
        float v=0.f; for (int i=0;i<S0_;++i){ float d=c0v[i]-m; v += d*d; } v *= (1.0f/S0_);
        st[0]=m; st[1]=rsqrtf(v+1e-5f);
        m=0.f; for (int i=0;i<S1_;++i) m += c1v[i]; m *= (1.0f/S1_);
        v=0.f; for (int i=0;i<S1_;++i){ float d=c1v[i]-m; v += d*d; } v *= (1.0f/S1_);
        st[2]=m; st[3]=rsqrtf(v+1e-5f);
    }
    __syncthreads();
    if (t < S0_) out_c0[b*S0_ + t] = (c0v[t]-st[0])*st[1];
    else if (t < S0_+S1_) out_c1[b*S1_ + (t-S0_)] = (c1v[t-S0_]-st[2])*st[3];
}

extern "C" void kernel_launch(void* const* d_in, const int* in_sizes, int n_in,
                              void* d_out, int out_size, void* d_ws, size_t ws_size,
                              hipStream_t stream)
{
    const float* h   = (const float*)d_in[0];
    const float* Wp  = (const float*)d_in[1];
    const float* bp  = (const float*)d_in[2];
    const float* Wsub= (const float*)d_in[3];
    const float* bs  = (const float*)d_in[4];
    const float* Wq  = (const float*)d_in[5];
    const float* bq  = (const float*)d_in[6];
    const float* Wk  = (const float*)d_in[7];
    const float* bk  = (const float*)d_in[8];
    const float* Wv  = (const float*)d_in[9];
    const float* bv  = (const float*)d_in[10];
    const float* Wo  = (const float*)d_in[11];
    const float* bo  = (const float*)d_in[12];
    const float* Wfs = (const float*)d_in[13];
    const float* bfs = (const float*)d_in[14];
    const float* Wpc = (const float*)d_in[15];
    const float* bpc = (const float*)d_in[16];
    const float* Wc0 = (const float*)d_in[17];
    const float* bc0 = (const float*)d_in[18];
    const float* Wc1 = (const float*)d_in[19];
    const float* bc1 = (const float*)d_in[20];

    float* out = (float*)d_out;
    float* out_pl = out;                         // [256,1000]
    float* out_c0 = out + 256000;                // [256,10]
    float* out_c1 = out + 258560;                // [256,20]
    float* out_fs = out + 263680;                // [256,196,256]
    float* out_se = out + 13108736;              // [256,196,256]

    // ---- workspace: 8 bf16 units (slots 0-3 = hb, 4-7 time-shared) ----
    ushort_t* U = (ushort_t*)d_ws;
    const size_t UN = (size_t)ROWS * D_;         // 12,845,056
    ushort_t* hb   = U + 0*UN;                   // bf16(h), spans 4 UN
    ushort_t* s4   = U + 4*UN;                   // pe
    ushort_t* s5   = U + 5*UN;                   // se (K and V for attn)
    ushort_t* s6   = U + 6*UN;                   // q'' -> integ
    ushort_t* s7   = U + 7*UN;                   // ao'

    float* fmisc = (float*)(U + 8*UN);
    float* rowm = fmisc;                          // 50176
    float* rowr = rowm + ROWS;                    // 50176
    float* wsmb = rowr + ROWS;                    // 256
    float* pooled = wsmb + D_;                    // 65536
    float* sp   = pooled + (size_t)B_*D_;         // 65536
    float* mbar = sp + (size_t)B_*D_;             // 256
    float* bqk  = mbar + 256;                     // 256
    float* bvo  = bqk + 256;                      // 256
    float* Abar = bvo + 256;                      // 327680
    float* Apart = Abar + (size_t)B_*CAT;         // 256*4*1344
    int*   yhat = (int*)(Apart + (size_t)B_*4*APLD);
    ushort_t* wp = (ushort_t*)(yhat + 512);
    ushort_t* WpsH = wp;               // [512][1024]
    ushort_t* WfsH = WpsH + 524288;    // [256][1280]
    ushort_t* WqkH = WfsH + 327680;    // [256][256]
    ushort_t* WvoH = WqkH + 65536;     // [256][256]

    // convert h + fused weight prep (incl. folded Wqk/Wvo + wsum)
    cvt8_kernel<<<25088, 256, 0, stream>>>(h, hb);
    prep_kernel<<<3904, 256, 0, stream>>>(Wp, Wsub, Wfs, Wq, Wk, bq, Wo, Wv, bv, bo,
                                          WpsH, WfsH, WqkH, WvoH, wsmb, bqk, bvo);

    // fused pe+se -> pe s4, se f32 out_se + bf16 s5   (grid 784)
    gemm_bf<32,32,2,7><<<784, 512, 0, stream>>>(
        hb, hb, IN_, IN_, WpsH, IN_, bp, bs,
        out_se, s4, s5, nullptr, nullptr, nullptr);
    // q'' = pe @ Wqk^T + bqk (scale folded; k never computed) -> s6   (grid 392)
    gemm_bf<8,8,1,3><<<392, 512, 0, stream>>>(
        s4, s4, D_, D_, WqkH, D_, bqk, nullptr,
        nullptr, s6, nullptr, nullptr, nullptr, nullptr);
    // attention with K = V = se  -> ao' s7
    attn_mfma<<<dim3(B_, H_), 256, 0, stream>>>(s6, s5, s5, s7);
    // integ = ao' @ Wvo^T + bvo (v never computed) -> bf16 s6   (grid 392)
    gemm_bf<8,8,1,3><<<392, 512, 0, stream>>>(
        s7, s7, D_, D_, WvoH, D_, bvo, nullptr,
        nullptr, s6, nullptr, nullptr, nullptr, nullptr);
    // fused LN stats + abar partial (bf16 h + bf16 integ)
    abar_part<<<dim3(B_,4), 256, 0, stream>>>(hb, s6, rowm, rowr, Apart);
    // fs (A = hb | integ bf16; LN folded) -> out_fs   (grid 392)
    gemm_bf<40,32,1,5><<<392, 512, 0, stream>>>(
        hb, s6, IN_, D_, WfsH, CAT, bfs, nullptr,
        out_fs, nullptr, nullptr, rowm, rowr, wsmb);
    // exact pooled via Abar identity
    abar_reduce<<<B_, 256, 0, stream>>>(Apart, Abar, mbar);
    pooled_kernel<<<B_, 256, 0, stream>>>(Abar, mbar, Wfs, wsmb, bfs, pooled);
    // sp from se (bf16)
    mean_tokens_bf<<<B_, 256, 0, stream>>>(s5, sp);
    // parent logits + routing
    parent_kernel<<<B_, 256, 0, stream>>>(pooled, Wpc, bpc, out_pl, yhat);
    // routed child classifiers
    child_kernel<<<B_, 64, 0, stream>>>(sp, yhat, Wc0, bc0, Wc1, bc1, out_c0, out_c1);
}

// Round 16
// 433.001 us; speedup vs baseline: 1.2459x; 1.0502x over previous
//
#include <hip/hip_runtime.h>
#include <hip/hip_bf16.h>
#include <math.h>

// Problem dims
#define B_   256
#define N_   196
#define IN_  1024
#define D_   256
#define H_   8
#define HD_  32
#define NC_  1000
#define S0_  10
#define S1_  20
#define ROWS (B_*N_)      // 50176
#define CAT  (IN_+D_)     // 1280

typedef unsigned short ushort_t;
typedef short bf16x8 __attribute__((ext_vector_type(8)));
typedef float f32x4  __attribute__((ext_vector_type(4)));
typedef ushort_t us4 __attribute__((ext_vector_type(4)));
typedef ushort_t us8 __attribute__((ext_vector_type(8)));

__device__ __forceinline__ ushort_t f2bf(float f){
    __hip_bfloat16 b = __float2bfloat16(f);
    ushort_t u; __builtin_memcpy(&u, &b, 2); return u;
}
__device__ __forceinline__ float bf2f(ushort_t h){
    union { unsigned int u; float f; } x; x.u = ((unsigned int)h) << 16;
    return x.f;
}
__device__ __forceinline__ float gelu_tanh(float x){
    float x3 = x*x*x;
    float inner = 0.7978845608028654f*(x + 0.044715f*x3);
    return 0.5f*x*(1.0f + tanhf(inner));
}

// ---------- async global->LDS, 16B per lane ----------
typedef __attribute__((address_space(1))) const unsigned int gu32;
typedef __attribute__((address_space(3))) unsigned int lu32;
__device__ __forceinline__ void gload_lds16b(const void* g, void* l){
    __builtin_amdgcn_global_load_lds((gu32*)g, (lu32*)l, 16, 0, 0);
}
// swizzle (refcheck'd r4-r15): LDS(row, slot') holds global (row, slot' ^ ((row>>1)&3));
// slots are 16B units; frag read XORs back.
__device__ __forceinline__ bf16x8 frag32(const ushort_t* lds, int row, int fq){
    return *(const bf16x8*)&lds[row*32 + ((fq ^ ((row >> 1) & 3)) << 3)];
}

// ---------- fused h-convert + weight prep; grid 28992 ----------
// b < 25088: h f32 -> hb bf16 (8 elems/thread)
// else: weight converts + colsum(Wfs) + folded Wqk/Wvo (prep grid offset 25088)
__global__ __launch_bounds__(256)
void prep_all(const float* __restrict__ h, ushort_t* __restrict__ hb,
              const float* __restrict__ Wp, const float* __restrict__ Wsub,
              const float* __restrict__ Wfs,
              const float* __restrict__ Wq, const float* __restrict__ Wk,
              const float* __restrict__ bq,
              const float* __restrict__ Wo, const float* __restrict__ Wv,
              const float* __restrict__ bv, const float* __restrict__ bo,
              ushort_t* __restrict__ WpsH, ushort_t* __restrict__ WfsH,
              ushort_t* __restrict__ WqkH, ushort_t* __restrict__ WvoH,
              float* __restrict__ wsum, float* __restrict__ bqk,
              float* __restrict__ bvo)
{
    const int bid = blockIdx.x, t = threadIdx.x;
    if (bid < 25088){
        size_t i = ((size_t)bid*256 + t)*8;
        float4 a = *(const float4*)(h + i);
        float4 b = *(const float4*)(h + i + 4);
        us8 o;
        o[0]=f2bf(a.x); o[1]=f2bf(a.y); o[2]=f2bf(a.z); o[3]=f2bf(a.w);
        o[4]=f2bf(b.x); o[5]=f2bf(b.y); o[6]=f2bf(b.z); o[7]=f2bf(b.w);
        *(us8*)(hb + i) = o;
        return;
    }
    const int b = bid - 25088;
    if (b < 1024){ int i=b*256+t; WpsH[i] = f2bf(Wp[i]); }
    else if (b < 2048){ int i=(b-1024)*256+t; WpsH[262144+i] = f2bf(Wsub[i]); }
    else if (b < 3328){ int i=(b-2048)*256+t; WfsH[i] = f2bf(Wfs[i]); }
    else if (b < 3392){
        int d = (b-3328)*4 + (t>>6), l = t & 63;
        const float* w = Wfs + (size_t)d*CAT;
        float s = 0.f;
        #pragma unroll
        for (int c0=0;c0<CAT;c0+=256){
            float4 v = *(const float4*)(w + c0 + l*4);
            s += v.x+v.y+v.z+v.w;
        }
        #pragma unroll
        for (int off=32;off>0;off>>=1) s += __shfl_down(s, off);
        if (l == 0) wsum[d] = s;
    }
    else if (b < 3648){
        // Wqk[c][d] = s*Σ_e Wq[e][d]·Wk[e][c];  bqk[c] = s*Σ_e bq[e]·Wk[e][c]
        const int c = b - 3392, d = t;
        const float sc = 0.17677669529663687f;
        float acc = 0.f, accb = 0.f;
        for (int e = 0; e < 256; ++e){
            float wkc = Wk[e*256 + c];
            acc  += Wq[e*256 + d] * wkc;
            accb += bq[e] * wkc;
        }
        WqkH[c*256 + d] = f2bf(acc * sc);
        if (d == 0) bqk[c] = accb * sc;
    }
    else {
        // Wvo[e2][c] = Σ_e Wo[e2][e]·Wv[e][c];  bvo[e2] = Wo[e2]·bv + bo[e2]
        const int e2 = b - 3648, c = t;
        float acc = 0.f, accb = 0.f;
        for (int e = 0; e < 256; ++e){
            float woe = Wo[e2*256 + e];
            acc  += woe * Wv[e*256 + c];
            accb += woe * bv[e];
        }
        WvoH[e2*256 + c] = f2bf(acc);
        if (c == 0) bvo[e2] = accb + bo[e2];
    }
}

// ---------- 3-deep counted-vmcnt pipelined bf16 GEMM (addr-hoisted + setprio) ----------
// 128x256 tile, 8 waves (2x4), BK=32, 3 LDS buffers (72KB).
// EPI: 7=pese(gelu; col<256->pe o1h, else seF f32o + se o2h)
//      3=plain bf16(o1h)  5=fs(LN-fold->f32o)
template<int KCH, int KCH1, int NBN, int EPI>
__global__ __launch_bounds__(512, 4)
void gemm_bf(const ushort_t* __restrict__ A1b, const ushort_t* __restrict__ A2b,
             int lda1, int lda2,
             const ushort_t* __restrict__ BH, int ldb,
             const float* __restrict__ bias1, const float* __restrict__ bias2,
             float* __restrict__ f32o, ushort_t* __restrict__ o1h, ushort_t* __restrict__ o2h,
             const float* __restrict__ rowm, const float* __restrict__ rowr,
             const float* __restrict__ wsump)
{
    __shared__ ushort_t SA[3][128*32];   // 3 x 8 KB
    __shared__ ushort_t SB[3][256*32];   // 3 x 16 KB
    const int nwg = gridDim.x, cpx = nwg >> 3, bid = blockIdx.x;
    const int wg = (bid & 7)*cpx + (bid >> 3);
    const int bn = (wg % NBN)*256, bm = (wg / NBN)*128;
    const int t = threadIdx.x, lane = t & 63, wid = t >> 6;
    const int wr = wid >> 2, wc = wid & 3, fr = lane & 15, fq = lane >> 4;

    // hoisted per-lane staging pointers; advance 64B (=32 ushorts) per staged chunk
    const int rr = lane >> 2;
    const int sl = (lane & 3) ^ ((lane >> 3) & 3);
    const ushort_t* srcA  = A1b + (size_t)(bm + wid*16 + rr)*lda1 + sl*8;
    const ushort_t* srcB0 = BH  + (size_t)(bn + wid*32 + rr)*ldb  + sl*8;
    const ushort_t* srcB1 = srcB0 + (size_t)16*ldb;

    f32x4 acc[4][4];
    #pragma unroll
    for (int i=0;i<4;++i)
        #pragma unroll
        for (int j=0;j<4;++j) acc[i][j] = (f32x4){0.f,0.f,0.f,0.f};

    auto stageT = [&](int buf, int kc){     // 3 vmem instrs per wave
        if (KCH1 < KCH && kc == KCH1)
            srcA = A2b + (size_t)(bm + wid*16 + rr)*lda2 + sl*8;
        gload_lds16b(srcA,  &SA[buf][wid*512]);
        gload_lds16b(srcB0, &SB[buf][wid*1024]);
        gload_lds16b(srcB1, &SB[buf][wid*1024 + 512]);
        srcA += 32; srcB0 += 32; srcB1 += 32;
    };
    auto compute = [&](int buf){
        bf16x8 a[4], b[4];
        #pragma unroll
        for (int i=0;i<4;++i){
            a[i] = frag32(SA[buf], wr*64 + i*16 + fr, fq);
            b[i] = frag32(SB[buf], wc*64 + i*16 + fr, fq);
        }
        __builtin_amdgcn_s_setprio(1);
        #pragma unroll
        for (int i=0;i<4;++i)
            #pragma unroll
            for (int j=0;j<4;++j)
                acc[i][j] = __builtin_amdgcn_mfma_f32_16x16x32_bf16(a[i], b[j], acc[i][j], 0,0,0);
        __builtin_amdgcn_s_setprio(0);
    };

    // prologue: 3 tiles in flight; wait only tile 0
    stageT(0, 0);
    stageT(1, 1);
    stageT(2, 2);
    asm volatile("s_waitcnt vmcnt(6)" ::: "memory");
    __builtin_amdgcn_sched_barrier(0);
    __builtin_amdgcn_s_barrier();

    int cur = 0;
    for (int kc = 0; kc < KCH; ++kc){
        compute(cur);
        if (kc + 1 >= KCH) break;
        asm volatile("s_waitcnt lgkmcnt(0)" ::: "memory");   // this wave's ds_reads retired
        __builtin_amdgcn_s_barrier();                        // all waves done reading buf cur
        if (kc + 3 < KCH){
            stageT(cur, kc + 3);                             // refill freed buffer
            asm volatile("s_waitcnt vmcnt(6)" ::: "memory"); // wait tile kc+1 only
        } else if (kc + 2 < KCH){
            asm volatile("s_waitcnt vmcnt(3)" ::: "memory");
        } else {
            asm volatile("s_waitcnt vmcnt(0)" ::: "memory");
        }
        __builtin_amdgcn_sched_barrier(0);
        __builtin_amdgcn_s_barrier();                        // tile kc+1 visible to all
        cur = (cur == 2) ? 0 : cur + 1;
    }

    // epilogue
    #pragma unroll
    for (int i=0;i<4;++i){
        #pragma unroll
        for (int j=0;j<4;++j){
            const int col = bn + wc*64 + j*16 + fr;
            #pragma unroll
            for (int r=0;r<4;++r){
                const int row = bm + wr*64 + i*16 + fq*4 + r;
                float x = acc[i][j][r];
                if (EPI == 7){
                    if (col < 256){
                        float y = gelu_tanh(x + bias1[col]);
                        o1h[(size_t)row*D_ + col] = f2bf(y);
                    } else {
                        float y = gelu_tanh(x + bias2[col-256]);
                        f32o[(size_t)row*D_ + (col-256)] = y;
                        o2h[(size_t)row*D_ + (col-256)] = f2bf(y);
                    }
                } else if (EPI == 3){
                    o1h[(size_t)row*D_ + col] = f2bf(x + bias1[col]);
                } else { // EPI == 5
                    f32o[(size_t)row*D_ + col] = rowr[row]*(x - rowm[row]*wsump[col]) + bias1[col];
                }
            }
        }
    }
}

// ---------- MFMA attention (bf16 in, bf16 out); K and V are both se ----------
#define KROWS 208
#define KLD   40
#define VLD   232

__global__ __launch_bounds__(256)
void attn_mfma(const ushort_t* __restrict__ qhi,
               const ushort_t* __restrict__ khi,
               const ushort_t* __restrict__ vhi,
               ushort_t* __restrict__ aohi)
{
    __shared__ ushort_t Khi[KROWS*KLD];
    __shared__ ushort_t Vthi[32*VLD];

    const int b = blockIdx.x, hh = blockIdx.y;
    const int t = threadIdx.x;
    const int lane = t & 63;
    const int wid  = t >> 6;
    const int fr = lane & 15;
    const int fq = lane >> 4;
    const size_t bbase = (size_t)b*N_*D_ + hh*HD_;

    for (int idx = t; idx < KROWS*4; idx += 256){
        int row = idx >> 2, c8 = (idx & 3) << 3;
        us8 vh;
        if (row < N_){
            vh = *(const us8*)(khi + bbase + (size_t)row*D_ + c8);
        } else {
            #pragma unroll
            for (int j=0;j<8;++j) vh[j]=0;
        }
        *(us8*)&Khi[row*KLD + c8] = vh;
    }
    for (int idx = t; idx < 224*4; idx += 256){
        int key = idx >> 2, c8 = (idx & 3) << 3;
        us8 vh;
        if (key < N_){
            vh = *(const us8*)(vhi + bbase + (size_t)key*D_ + c8);
        } else {
            #pragma unroll
            for (int j=0;j<8;++j) vh[j]=0;
        }
        int w = key & 31, cc = key >> 5;
        int slot;
        if (w < 16) slot = cc*32 + (w>>2)*8 + (w&3);
        else { int w2 = w-16; slot = cc*32 + (w2>>2)*8 + 4 + (w2&3); }
        #pragma unroll
        for (int j=0;j<8;++j)
            Vthi[(c8 + j)*VLD + slot] = vh[j];
    }
    __syncthreads();

    for (int qt = wid; qt < 13; qt += 4){
        int qrow = qt*16 + fr; if (qrow > N_-1) qrow = N_-1;
        const bf16x8 qh = *(const bf16x8*)(qhi + bbase + (size_t)qrow*D_ + fq*8);

        f32x4 s[13];
        #pragma unroll
        for (int kt=0; kt<13; ++kt) s[kt] = (f32x4){0.f,0.f,0.f,0.f};
        #pragma unroll
        for (int kt=0; kt<13; ++kt){
            const bf16x8 kh = *(const bf16x8*)&Khi[(kt*16 + fr)*KLD + fq*8];
            s[kt] = __builtin_amdgcn_mfma_f32_16x16x32_bf16(kh, qh, s[kt], 0,0,0);
        }
        if (fq > 0) s[12] = (f32x4){-1e30f,-1e30f,-1e30f,-1e30f};

        float m = -3.4e38f;
        #pragma unroll
        for (int kt=0; kt<13; ++kt)
            #pragma unroll
            for (int r=0;r<4;++r) m = fmaxf(m, s[kt][r]);
        m = fmaxf(m, __shfl_xor(m, 16));
        m = fmaxf(m, __shfl_xor(m, 32));
        float sum = 0.f;
        #pragma unroll
        for (int kt=0; kt<13; ++kt)
            #pragma unroll
            for (int r=0;r<4;++r){
                float p = __expf(s[kt][r] - m);
                s[kt][r] = p; sum += p;
            }
        sum += __shfl_xor(sum, 16);
        sum += __shfl_xor(sum, 32);
        const float inv = 1.0f / sum;

        f32x4 o0 = (f32x4){0.f,0.f,0.f,0.f};
        f32x4 o1 = (f32x4){0.f,0.f,0.f,0.f};
        #pragma unroll
        for (int c=0;c<7;++c){
            bf16x8 ph;
            #pragma unroll
            for (int r=0;r<4;++r){
                ph[r]   = (short)f2bf(s[2*c][r]);
                ph[4+r] = (short)((c < 6) ? f2bf(s[2*c+1][r]) : 0);
            }
            const int coff = c*32 + fq*8;
            const bf16x8 v0h = *(const bf16x8*)&Vthi[(fr)*VLD + coff];
            const bf16x8 v1h = *(const bf16x8*)&Vthi[(16+fr)*VLD + coff];
            o0 = __builtin_amdgcn_mfma_f32_16x16x32_bf16(v0h, ph, o0, 0,0,0);
            o1 = __builtin_amdgcn_mfma_f32_16x16x32_bf16(v1h, ph, o1, 0,0,0);
        }
        int tok = qt*16 + fr;
        if (tok < N_){
            const size_t obase = bbase + (size_t)tok*D_;
            #pragma unroll
            for (int r=0;r<4;++r){
                aohi[obase + fq*4 + r]      = f2bf(o0[r]*inv);
                aohi[obase + 16 + fq*4 + r] = f2bf(o1[r]*inv);
            }
        }
    }
}

// ---------- fused rowstats + abar partial, wave-per-row (bf16 h + bf16 integ) ----------
#define APLD 1344
__global__ __launch_bounds__(256)
void abar_part(const ushort_t* __restrict__ hb, const ushort_t* __restrict__ integb,
               float* __restrict__ rowm, float* __restrict__ rowr,
               float* __restrict__ Apart)
{
    const int b = blockIdx.x, qq = blockIdx.y, t = threadIdx.x;
    const int l = t & 63, w = t >> 6;
    const int n0 = qq*49;
    float4 acc[5];
    #pragma unroll
    for (int ch=0; ch<5; ++ch) acc[ch] = (float4){0.f,0.f,0.f,0.f};
    float mracc = 0.f;
    for (int n = w; n < 49; n += 4){
        const int row = b*N_ + n0 + n;
        const ushort_t* hr = hb + (size_t)row*IN_;
        float4 e[5];
        #pragma unroll
        for (int ch=0; ch<4; ++ch){
            us4 iv = *(const us4*)(hr + ch*256 + l*4);
            e[ch].x = bf2f(iv[0]); e[ch].y = bf2f(iv[1]);
            e[ch].z = bf2f(iv[2]); e[ch].w = bf2f(iv[3]);
        }
        {
            us4 iv = *(const us4*)(integb + (size_t)row*D_ + l*4);
            e[4].x = bf2f(iv[0]); e[4].y = bf2f(iv[1]);
            e[4].z = bf2f(iv[2]); e[4].w = bf2f(iv[3]);
        }
        float s = 0.f, s2 = 0.f;
        #pragma unroll
        for (int ch=0; ch<5; ++ch){
            s  += e[ch].x + e[ch].y + e[ch].z + e[ch].w;
            s2 += e[ch].x*e[ch].x + e[ch].y*e[ch].y + e[ch].z*e[ch].z + e[ch].w*e[ch].w;
        }
        #pragma unroll
        for (int off=32; off>0; off>>=1){ s += __shfl_xor(s, off); s2 += __shfl_xor(s2, off); }
        float m  = s * (1.0f/CAT);
        float rr = rsqrtf(s2 * (1.0f/CAT) - m*m + 1e-5f);
        if (l == 0){ rowm[row] = m; rowr[row] = rr; }
        #pragma unroll
        for (int ch=0; ch<5; ++ch){
            acc[ch].x += rr*e[ch].x; acc[ch].y += rr*e[ch].y;
            acc[ch].z += rr*e[ch].z; acc[ch].w += rr*e[ch].w;
        }
        mracc += rr*m;
    }
    __shared__ float part[4][CAT];
    __shared__ float pm[4];
    #pragma unroll
    for (int ch=0; ch<4; ++ch) *(float4*)&part[w][ch*256 + l*4] = acc[ch];
    *(float4*)&part[w][IN_ + l*4] = acc[4];
    if (l == 0) pm[w] = mracc;
    __syncthreads();
    float* ap = Apart + ((size_t)b*4 + qq)*APLD;
    for (int c = t; c < 1280; c += 256)
        ap[c] = part[0][c] + part[1][c] + part[2][c] + part[3][c];
    if (t == 0) ap[1280] = pm[0] + pm[1] + pm[2] + pm[3];
}

// ---------- fused tail1: (b<256) Abar-reduce + pooled; (b>=256) se-mean ----------
__global__ __launch_bounds__(256)
void tail1_kernel(const float* __restrict__ Apart,
                  const float* __restrict__ Wfs, const float* __restrict__ wsum,
                  const float* __restrict__ bfs,
                  const ushort_t* __restrict__ seb,
                  float* __restrict__ pooled, float* __restrict__ sp)
{
    const int b0 = blockIdx.x, t = threadIdx.x;
    if (b0 < 256){
        const int b = b0;
        __shared__ float ab[CAT];
        __shared__ float mb;
        const float* ap = Apart + (size_t)b*4*APLD;
        for (int c = t; c < 1280; c += 256)
            ab[c] = (ap[c] + ap[APLD+c] + ap[2*APLD+c] + ap[3*APLD+c]) * (1.f/N_);
        if (t == 0)
            mb = (ap[1280] + ap[APLD+1280] + ap[2*APLD+1280] + ap[3*APLD+1280]) * (1.f/N_);
        __syncthreads();
        const int d = t;
        const float* w = Wfs + (size_t)d*CAT;
        float s = 0.f;
        for (int c=0;c<CAT;c+=4){
            float4 wv = *(const float4*)(w+c);
            s += ab[c]*wv.x + ab[c+1]*wv.y + ab[c+2]*wv.z + ab[c+3]*wv.w;
        }
        pooled[b*D_ + d] = s - mb*wsum[d] + bfs[d];
    } else {
        const int b = b0 - 256, d = t;
        const ushort_t* p = seb + (size_t)b*N_*D_ + d;
        float s = 0.f;
        for (int n=0;n<N_;++n) s += bf2f(p[(size_t)n*D_]);
        sp[b*D_ + d] = s * (1.0f/N_);
    }
}

// ---------- fused parent logits + routing + child classifiers ----------
__global__ __launch_bounds__(256)
void parent_child_kernel(const float* __restrict__ pooled, const float* __restrict__ Wpc,
                         const float* __restrict__ bpc, const float* __restrict__ sp,
                         const float* __restrict__ Wc0, const float* __restrict__ bc0,
                         const float* __restrict__ Wc1, const float* __restrict__ bc1,
                         float* __restrict__ out, float* __restrict__ out_c0,
                         float* __restrict__ out_c1)
{
    const int b = blockIdx.x, t = threadIdx.x;
    __shared__ __align__(16) float pl[D_];
    __shared__ float spl[D_];
    __shared__ float lg[NC_];
    pl[t]  = pooled[b*D_ + t];
    spl[t] = sp[b*D_ + t];
    __syncthreads();
    for (int c = t; c < NC_; c += 256){
        const float4* w4 = (const float4*)(Wpc + (size_t)c*D_);
        float s = 0.f;
        #pragma unroll 16
        for (int j=0;j<64;++j){
            float4 wv = w4[j];
            s += pl[j*4]*wv.x + pl[j*4+1]*wv.y + pl[j*4+2]*wv.z + pl[j*4+3]*wv.w;
        }
        lg[c] = s + bpc[c];
    }
    __syncthreads();
    float s=0.f, s2=0.f, bmv=-3.4e38f; int bidx=0;
    for (int c=t;c<NC_;c+=256){
        float x = lg[c]; s += x; s2 += x*x;
        if (x > bmv){ bmv=x; bidx=c; }
    }
    #pragma unroll
    for (int off=32; off>0; off>>=1){
        s  += __shfl_down(s, off);
        s2 += __shfl_down(s2, off);
        float ov = __shfl_down(bmv, off); int oi = __shfl_down(bidx, off);
        if (ov > bmv || (ov == bmv && oi < bidx)){ bmv=ov; bidx=oi; }
    }
    __shared__ float rs[4], rs2[4], rmv[4]; __shared__ int ri[4];
    __shared__ float fm, fr_; __shared__ int ymy;
    int w = t >> 6;
    if ((t & 63) == 0){ rs[w]=s; rs2[w]=s2; rmv[w]=bmv; ri[w]=bidx; }
    __syncthreads();
    if (t == 0){
        float S=0.f, S2=0.f, mv=-3.4e38f; int mi=0;
        for (int i=0;i<4;++i){
            S += rs[i]; S2 += rs2[i];
            if (rmv[i] > mv || (rmv[i] == mv && ri[i] < mi)){ mv=rmv[i]; mi=ri[i]; }
        }
        float mean = S*(1.0f/NC_);
        float var  = S2*(1.0f/NC_) - mean*mean;
        fm = mean; fr_ = rsqrtf(var + 1e-5f);
        ymy = mi;
    }
    __syncthreads();
    for (int c=t;c<NC_;c+=256) out[(size_t)b*NC_ + c] = (lg[c]-fm)*fr_;

    // ---- child classifiers (routed by ymy) ----
    const int y = ymy;
    __shared__ float c0v[S0_], c1v[S1_];
    if (t < S0_){
        const float* wp0 = Wc0 + (size_t)y*D_*S0_ + t;
        float acc = 0.f;
        for (int d=0;d<D_;++d) acc += spl[d]*wp0[(size_t)d*S0_];
        c0v[t] = acc + bc0[y*S0_ + t];
    } else if (t < S0_+S1_){
        int k = t - S0_;
        const float* wp1 = Wc1 + (size_t)y*D_*S1_ + k;
        float acc = 0.f;
        for (int d=0;d<D_;++d) acc += spl[d]*wp1[(size_t)d*S1_];
        c1v[k] = acc + bc1[y*S1_ + k];
    }
    __syncthreads();
    __shared__ float st[4];
    if (t == 0){
        float m=0.f; for (int i=0;i<S0_;++i) m += c0v[i]; m *= (1.0f/S0_);
        float v=0.f; for (int i=0;i<S0_;++i){ float d=c0v[i]-m; v += d*d; } v *= (1.0f/S0_);
        st[0]=m; st[1]=rsqrtf(v+1e-5f);
        m=0.f; for (int i=0;i<S1_;++i) m += c1v[i]; m *= (1.0f/S1_);
        v=0.f; for (int i=0;i<S1_;++i){ float d=c1v[i]-m; v += d*d; } v *= (1.0f/S1_);
        st[2]=m; st[3]=rsqrtf(v+1e-5f);
    }
    __syncthreads();
    if (t < S0_) out_c0[b*S0_ + t] = (c0v[t]-st[0])*st[1];
    else if (t < S0_+S1_) out_c1[b*S1_ + (t-S0_)] = (c1v[t-S0_]-st[2])*st[3];
}

extern "C" void kernel_launch(void* const* d_in, const int* in_sizes, int n_in,
                              void* d_out, int out_size, void* d_ws, size_t ws_size,
                              hipStream_t stream)
{
    const float* h   = (const float*)d_in[0];
    const float* Wp  = (const float*)d_in[1];
    const float* bp  = (const float*)d_in[2];
    const float* Wsub= (const float*)d_in[3];
    const float* bs  = (const float*)d_in[4];
    const float* Wq  = (const float*)d_in[5];
    const float* bq  = (const float*)d_in[6];
    const float* Wk  = (const float*)d_in[7];
    const float* bk  = (const float*)d_in[8];
    const float* Wv  = (const float*)d_in[9];
    const float* bv  = (const float*)d_in[10];
    const float* Wo  = (const float*)d_in[11];
    const float* bo  = (const float*)d_in[12];
    const float* Wfs = (const float*)d_in[13];
    const float* bfs = (const float*)d_in[14];
    const float* Wpc = (const float*)d_in[15];
    const float* bpc = (const float*)d_in[16];
    const float* Wc0 = (const float*)d_in[17];
    const float* bc0 = (const float*)d_in[18];
    const float* Wc1 = (const float*)d_in[19];
    const float* bc1 = (const float*)d_in[20];

    float* out = (float*)d_out;
    float* out_pl = out;                         // [256,1000]
    float* out_c0 = out + 256000;                // [256,10]
    float* out_c1 = out + 258560;                // [256,20]
    float* out_fs = out + 263680;                // [256,196,256]
    float* out_se = out + 13108736;              // [256,196,256]

    // ---- workspace: 8 bf16 units (slots 0-3 = hb, 4-7 time-shared) ----
    ushort_t* U = (ushort_t*)d_ws;
    const size_t UN = (size_t)ROWS * D_;         // 12,845,056
    ushort_t* hb   = U + 0*UN;                   // bf16(h), spans 4 UN
    ushort_t* s4   = U + 4*UN;                   // pe
    ushort_t* s5   = U + 5*UN;                   // se (K and V for attn)
    ushort_t* s6   = U + 6*UN;                   // q'' -> integ
    ushort_t* s7   = U + 7*UN;                   // ao'

    float* fmisc = (float*)(U + 8*UN);
    float* rowm = fmisc;                          // 50176
    float* rowr = rowm + ROWS;                    // 50176
    float* wsmb = rowr + ROWS;                    // 256
    float* pooled = wsmb + D_;                    // 65536
    float* sp   = pooled + (size_t)B_*D_;         // 65536
    float* bqk  = sp + (size_t)B_*D_;             // 256
    float* bvo  = bqk + 256;                      // 256
    float* Apart = bvo + 256;                     // 256*4*1344
    ushort_t* wp = (ushort_t*)(Apart + (size_t)B_*4*APLD);
    ushort_t* WpsH = wp;               // [512][1024]
    ushort_t* WfsH = WpsH + 524288;    // [256][1280]
    ushort_t* WqkH = WfsH + 327680;    // [256][256]
    ushort_t* WvoH = WqkH + 65536;     // [256][256]

    // fused h-convert + weight prep (incl. folded Wqk/Wvo + wsum)
    prep_all<<<28992, 256, 0, stream>>>(h, hb, Wp, Wsub, Wfs, Wq, Wk, bq, Wo, Wv, bv, bo,
                                        WpsH, WfsH, WqkH, WvoH, wsmb, bqk, bvo);

    // fused pe+se -> pe s4, se f32 out_se + bf16 s5   (grid 784)
    gemm_bf<32,32,2,7><<<784, 512, 0, stream>>>(
        hb, hb, IN_, IN_, WpsH, IN_, bp, bs,
        out_se, s4, s5, nullptr, nullptr, nullptr);
    // q'' = pe @ Wqk^T + bqk (scale folded; k never computed) -> s6   (grid 392)
    gemm_bf<8,8,1,3><<<392, 512, 0, stream>>>(
        s4, s4, D_, D_, WqkH, D_, bqk, nullptr,
        nullptr, s6, nullptr, nullptr, nullptr, nullptr);
    // attention with K = V = se  -> ao' s7
    attn_mfma<<<dim3(B_, H_), 256, 0, stream>>>(s6, s5, s5, s7);
    // integ = ao' @ Wvo^T + bvo (v never computed) -> bf16 s6   (grid 392)
    gemm_bf<8,8,1,3><<<392, 512, 0, stream>>>(
        s7, s7, D_, D_, WvoH, D_, bvo, nullptr,
        nullptr, s6, nullptr, nullptr, nullptr, nullptr);
    // fused LN stats + abar partial (bf16 h + bf16 integ)
    abar_part<<<dim3(B_,4), 256, 0, stream>>>(hb, s6, rowm, rowr, Apart);
    // fs (A = hb | integ bf16; LN folded) -> out_fs   (grid 392)
    gemm_bf<40,32,1,5><<<392, 512, 0, stream>>>(
        hb, s6, IN_, D_, WfsH, CAT, bfs, nullptr,
        out_fs, nullptr, nullptr, rowm, rowr, wsmb);
    // fused Abar-reduce+pooled (b<256) and se-mean (b>=256)
    tail1_kernel<<<512, 256, 0, stream>>>(Apart, Wfs, wsmb, bfs, s5, pooled, sp);
    // fused parent logits + routing + child classifiers
    parent_child_kernel<<<B_, 256, 0, stream>>>(pooled, Wpc, bpc, sp,
                                                Wc0, bc0, Wc1, bc1,
                                                out_pl, out_c0, out_c1);
}

// Round 17
// 414.520 us; speedup vs baseline: 1.3014x; 1.0446x over previous
//
#include <hip/hip_runtime.h>
#include <hip/hip_bf16.h>
#include <math.h>

// Problem dims
#define B_   256
#define N_   196
#define IN_  1024
#define D_   256
#define H_   8
#define HD_  32
#define NC_  1000
#define S0_  10
#define S1_  20
#define ROWS (B_*N_)      // 50176
#define CAT  (IN_+D_)     // 1280

typedef unsigned short ushort_t;
typedef short bf16x8 __attribute__((ext_vector_type(8)));
typedef float f32x4  __attribute__((ext_vector_type(4)));
typedef ushort_t us4 __attribute__((ext_vector_type(4)));
typedef ushort_t us8 __attribute__((ext_vector_type(8)));

__device__ __forceinline__ ushort_t f2bf(float f){
    __hip_bfloat16 b = __float2bfloat16(f);
    ushort_t u; __builtin_memcpy(&u, &b, 2); return u;
}
__device__ __forceinline__ float bf2f(ushort_t h){
    union { unsigned int u; float f; } x; x.u = ((unsigned int)h) << 16;
    return x.f;
}
__device__ __forceinline__ float gelu_tanh(float x){
    float x3 = x*x*x;
    float inner = 0.7978845608028654f*(x + 0.044715f*x3);
    return 0.5f*x*(1.0f + tanhf(inner));
}

// ---------- async global->LDS, 16B per lane ----------
typedef __attribute__((address_space(1))) const unsigned int gu32;
typedef __attribute__((address_space(3))) unsigned int lu32;
__device__ __forceinline__ void gload_lds16b(const void* g, void* l){
    __builtin_amdgcn_global_load_lds((gu32*)g, (lu32*)l, 16, 0, 0);
}
// swizzle (refcheck'd r4-r16): LDS(row, slot') holds global (row, slot' ^ ((row>>1)&3));
// slots are 16B units; frag read XORs back.
__device__ __forceinline__ bf16x8 frag32(const ushort_t* lds, int row, int fq){
    return *(const bf16x8*)&lds[row*32 + ((fq ^ ((row >> 1) & 3)) << 3)];
}

// ---------- fused h-convert + weight prep; grid 28992 ----------
__global__ __launch_bounds__(256)
void prep_all(const float* __restrict__ h, ushort_t* __restrict__ hb,
              const float* __restrict__ Wp, const float* __restrict__ Wsub,
              const float* __restrict__ Wfs,
              const float* __restrict__ Wq, const float* __restrict__ Wk,
              const float* __restrict__ bq,
              const float* __restrict__ Wo, const float* __restrict__ Wv,
              const float* __restrict__ bv, const float* __restrict__ bo,
              ushort_t* __restrict__ WpsH, ushort_t* __restrict__ WfsH,
              ushort_t* __restrict__ WqkH, ushort_t* __restrict__ WvoH,
              float* __restrict__ wsum, float* __restrict__ bqk,
              float* __restrict__ bvo)
{
    const int bid = blockIdx.x, t = threadIdx.x;
    if (bid < 25088){
        size_t i = ((size_t)bid*256 + t)*8;
        float4 a = *(const float4*)(h + i);
        float4 b = *(const float4*)(h + i + 4);
        us8 o;
        o[0]=f2bf(a.x); o[1]=f2bf(a.y); o[2]=f2bf(a.z); o[3]=f2bf(a.w);
        o[4]=f2bf(b.x); o[5]=f2bf(b.y); o[6]=f2bf(b.z); o[7]=f2bf(b.w);
        *(us8*)(hb + i) = o;
        return;
    }
    const int b = bid - 25088;
    if (b < 1024){ int i=b*256+t; WpsH[i] = f2bf(Wp[i]); }
    else if (b < 2048){ int i=(b-1024)*256+t; WpsH[262144+i] = f2bf(Wsub[i]); }
    else if (b < 3328){ int i=(b-2048)*256+t; WfsH[i] = f2bf(Wfs[i]); }
    else if (b < 3392){
        int d = (b-3328)*4 + (t>>6), l = t & 63;
        const float* w = Wfs + (size_t)d*CAT;
        float s = 0.f;
        #pragma unroll
        for (int c0=0;c0<CAT;c0+=256){
            float4 v = *(const float4*)(w + c0 + l*4);
            s += v.x+v.y+v.z+v.w;
        }
        #pragma unroll
        for (int off=32;off>0;off>>=1) s += __shfl_down(s, off);
        if (l == 0) wsum[d] = s;
    }
    else if (b < 3648){
        const int c = b - 3392, d = t;
        const float sc = 0.17677669529663687f;
        float acc = 0.f, accb = 0.f;
        for (int e = 0; e < 256; ++e){
            float wkc = Wk[e*256 + c];
            acc  += Wq[e*256 + d] * wkc;
            accb += bq[e] * wkc;
        }
        WqkH[c*256 + d] = f2bf(acc * sc);
        if (d == 0) bqk[c] = accb * sc;
    }
    else {
        const int e2 = b - 3648, c = t;
        float acc = 0.f, accb = 0.f;
        for (int e = 0; e < 256; ++e){
            float woe = Wo[e2*256 + e];
            acc  += woe * Wv[e*256 + c];
            accb += woe * bv[e];
        }
        WvoH[e2*256 + c] = f2bf(acc);
        if (c == 0) bvo[e2] = accb + bo[e2];
    }
}

// ---------- 2-deep counted-vmcnt GEMM, regs-first phase order ----------
// 128x256 tile, 8 waves (2x4), BK=32, 2 LDS buffers (48KB -> 3 blocks/CU).
// Per chunk: ds_read->regs; lgkmcnt(0); barrier; stage(cur<-kc+2); MFMA(regs);
// vmcnt(3) [tail 0]; barrier. Staging over cur is safe: barrier follows all
// waves' completed ds_reads. vmcnt ledger: 6 outstanding -> wait 3 (tile kc+1).
// EPI: 7=pese  3=plain bf16  5=fs(LN-fold)
template<int KCH, int KCH1, int NBN, int EPI>
__global__ __launch_bounds__(512, 4)
void gemm_bf(const ushort_t* __restrict__ A1b, const ushort_t* __restrict__ A2b,
             int lda1, int lda2,
             const ushort_t* __restrict__ BH, int ldb,
             const float* __restrict__ bias1, const float* __restrict__ bias2,
             float* __restrict__ f32o, ushort_t* __restrict__ o1h, ushort_t* __restrict__ o2h,
             const float* __restrict__ rowm, const float* __restrict__ rowr,
             const float* __restrict__ wsump)
{
    __shared__ ushort_t SA[2][128*32];   // 2 x 8 KB
    __shared__ ushort_t SB[2][256*32];   // 2 x 16 KB
    const int nwg = gridDim.x, cpx = nwg >> 3, bid = blockIdx.x;
    const int wg = (bid & 7)*cpx + (bid >> 3);
    const int bn = (wg % NBN)*256, bm = (wg / NBN)*128;
    const int t = threadIdx.x, lane = t & 63, wid = t >> 6;
    const int wr = wid >> 2, wc = wid & 3, fr = lane & 15, fq = lane >> 4;

    // hoisted per-lane staging pointers; advance 64B (=32 ushorts) per staged chunk
    const int rr = lane >> 2;
    const int sl = (lane & 3) ^ ((lane >> 3) & 3);
    const ushort_t* srcA  = A1b + (size_t)(bm + wid*16 + rr)*lda1 + sl*8;
    const ushort_t* srcB0 = BH  + (size_t)(bn + wid*32 + rr)*ldb  + sl*8;
    const ushort_t* srcB1 = srcB0 + (size_t)16*ldb;

    f32x4 acc[4][4];
    #pragma unroll
    for (int i=0;i<4;++i)
        #pragma unroll
        for (int j=0;j<4;++j) acc[i][j] = (f32x4){0.f,0.f,0.f,0.f};

    auto stageT = [&](int buf, int kc){     // 3 vmem instrs per wave
        if (KCH1 < KCH && kc == KCH1)
            srcA = A2b + (size_t)(bm + wid*16 + rr)*lda2 + sl*8;
        gload_lds16b(srcA,  &SA[buf][wid*512]);
        gload_lds16b(srcB0, &SB[buf][wid*1024]);
        gload_lds16b(srcB1, &SB[buf][wid*1024 + 512]);
        srcA += 32; srcB0 += 32; srcB1 += 32;
    };

    // prologue: 2 tiles in flight; wait only tile 0
    stageT(0, 0);
    stageT(1, 1);
    asm volatile("s_waitcnt vmcnt(3)" ::: "memory");
    __builtin_amdgcn_sched_barrier(0);
    __builtin_amdgcn_s_barrier();

    int cur = 0;
    for (int kc = 0; kc < KCH; ++kc){
        // 1) read fragments of current tile into registers
        bf16x8 a[4], b[4];
        #pragma unroll
        for (int i=0;i<4;++i){
            a[i] = frag32(SA[cur], wr*64 + i*16 + fr, fq);
            b[i] = frag32(SB[cur], wc*64 + i*16 + fr, fq);
        }
        asm volatile("s_waitcnt lgkmcnt(0)" ::: "memory");   // reads retired
        __builtin_amdgcn_sched_barrier(0);
        __builtin_amdgcn_s_barrier();                        // all waves done reading cur
        __builtin_amdgcn_sched_barrier(0);
        // 2) refill cur with tile kc+2 (issue), MFMA on regs overlaps the flight
        if (kc + 2 < KCH) stageT(cur, kc + 2);
        __builtin_amdgcn_s_setprio(1);
        #pragma unroll
        for (int i=0;i<4;++i)
            #pragma unroll
            for (int j=0;j<4;++j)
                acc[i][j] = __builtin_amdgcn_mfma_f32_16x16x32_bf16(a[i], b[j], acc[i][j], 0,0,0);
        __builtin_amdgcn_s_setprio(0);
        if (kc + 1 >= KCH) break;
        // 3) wait tile kc+1 landed, publish
        if (kc + 2 < KCH) asm volatile("s_waitcnt vmcnt(3)" ::: "memory");
        else              asm volatile("s_waitcnt vmcnt(0)" ::: "memory");
        __builtin_amdgcn_sched_barrier(0);
        __builtin_amdgcn_s_barrier();
        cur ^= 1;
    }

    // epilogue
    #pragma unroll
    for (int i=0;i<4;++i){
        #pragma unroll
        for (int j=0;j<4;++j){
            const int col = bn + wc*64 + j*16 + fr;
            #pragma unroll
            for (int r=0;r<4;++r){
                const int row = bm + wr*64 + i*16 + fq*4 + r;
                float x = acc[i][j][r];
                if (EPI == 7){
                    if (col < 256){
                        float y = gelu_tanh(x + bias1[col]);
                        o1h[(size_t)row*D_ + col] = f2bf(y);
                    } else {
                        float y = gelu_tanh(x + bias2[col-256]);
                        f32o[(size_t)row*D_ + (col-256)] = y;
                        o2h[(size_t)row*D_ + (col-256)] = f2bf(y);
                    }
                } else if (EPI == 3){
                    o1h[(size_t)row*D_ + col] = f2bf(x + bias1[col]);
                } else { // EPI == 5
                    f32o[(size_t)row*D_ + col] = rowr[row]*(x - rowm[row]*wsump[col]) + bias1[col];
                }
            }
        }
    }
}

// ---------- MFMA attention (bf16 in, bf16 out); K and V are both se ----------
#define KROWS 208
#define KLD   40
#define VLD   232

__global__ __launch_bounds__(256)
void attn_mfma(const ushort_t* __restrict__ qhi,
               const ushort_t* __restrict__ khi,
               const ushort_t* __restrict__ vhi,
               ushort_t* __restrict__ aohi)
{
    __shared__ ushort_t Khi[KROWS*KLD];
    __shared__ ushort_t Vthi[32*VLD];

    const int b = blockIdx.x, hh = blockIdx.y;
    const int t = threadIdx.x;
    const int lane = t & 63;
    const int wid  = t >> 6;
    const int fr = lane & 15;
    const int fq = lane >> 4;
    const size_t bbase = (size_t)b*N_*D_ + hh*HD_;

    for (int idx = t; idx < KROWS*4; idx += 256){
        int row = idx >> 2, c8 = (idx & 3) << 3;
        us8 vh;
        if (row < N_){
            vh = *(const us8*)(khi + bbase + (size_t)row*D_ + c8);
        } else {
            #pragma unroll
            for (int j=0;j<8;++j) vh[j]=0;
        }
        *(us8*)&Khi[row*KLD + c8] = vh;
    }
    for (int idx = t; idx < 224*4; idx += 256){
        int key = idx >> 2, c8 = (idx & 3) << 3;
        us8 vh;
        if (key < N_){
            vh = *(const us8*)(vhi + bbase + (size_t)key*D_ + c8);
        } else {
            #pragma unroll
            for (int j=0;j<8;++j) vh[j]=0;
        }
        int w = key & 31, cc = key >> 5;
        int slot;
        if (w < 16) slot = cc*32 + (w>>2)*8 + (w&3);
        else { int w2 = w-16; slot = cc*32 + (w2>>2)*8 + 4 + (w2&3); }
        #pragma unroll
        for (int j=0;j<8;++j)
            Vthi[(c8 + j)*VLD + slot] = vh[j];
    }
    __syncthreads();

    for (int qt = wid; qt < 13; qt += 4){
        int qrow = qt*16 + fr; if (qrow > N_-1) qrow = N_-1;
        const bf16x8 qh = *(const bf16x8*)(qhi + bbase + (size_t)qrow*D_ + fq*8);

        f32x4 s[13];
        #pragma unroll
        for (int kt=0; kt<13; ++kt) s[kt] = (f32x4){0.f,0.f,0.f,0.f};
        #pragma unroll
        for (int kt=0; kt<13; ++kt){
            const bf16x8 kh = *(const bf16x8*)&Khi[(kt*16 + fr)*KLD + fq*8];
            s[kt] = __builtin_amdgcn_mfma_f32_16x16x32_bf16(kh, qh, s[kt], 0,0,0);
        }
        if (fq > 0) s[12] = (f32x4){-1e30f,-1e30f,-1e30f,-1e30f};

        float m = -3.4e38f;
        #pragma unroll
        for (int kt=0; kt<13; ++kt)
            #pragma unroll
            for (int r=0;r<4;++r) m = fmaxf(m, s[kt][r]);
        m = fmaxf(m, __shfl_xor(m, 16));
        m = fmaxf(m, __shfl_xor(m, 32));
        float sum = 0.f;
        #pragma unroll
        for (int kt=0; kt<13; ++kt)
            #pragma unroll
            for (int r=0;r<4;++r){
                float p = __expf(s[kt][r] - m);
                s[kt][r] = p; sum += p;
            }
        sum += __shfl_xor(sum, 16);
        sum += __shfl_xor(sum, 32);
        const float inv = 1.0f / sum;

        f32x4 o0 = (f32x4){0.f,0.f,0.f,0.f};
        f32x4 o1 = (f32x4){0.f,0.f,0.f,0.f};
        #pragma unroll
        for (int c=0;c<7;++c){
            bf16x8 ph;
            #pragma unroll
            for (int r=0;r<4;++r){
                ph[r]   = (short)f2bf(s[2*c][r]);
                ph[4+r] = (short)((c < 6) ? f2bf(s[2*c+1][r]) : 0);
            }
            const int coff = c*32 + fq*8;
            const bf16x8 v0h = *(const bf16x8*)&Vthi[(fr)*VLD + coff];
            const bf16x8 v1h = *(const bf16x8*)&Vthi[(16+fr)*VLD + coff];
            o0 = __builtin_amdgcn_mfma_f32_16x16x32_bf16(v0h, ph, o0, 0,0,0);
            o1 = __builtin_amdgcn_mfma_f32_16x16x32_bf16(v1h, ph, o1, 0,0,0);
        }
        int tok = qt*16 + fr;
        if (tok < N_){
            const size_t obase = bbase + (size_t)tok*D_;
            #pragma unroll
            for (int r=0;r<4;++r){
                aohi[obase + fq*4 + r]      = f2bf(o0[r]*inv);
                aohi[obase + 16 + fq*4 + r] = f2bf(o1[r]*inv);
            }
        }
    }
}

// ---------- fused rowstats + abar partial, wave-per-row (bf16 h + bf16 integ) ----------
#define APLD 1344
__global__ __launch_bounds__(256)
void abar_part(const ushort_t* __restrict__ hb, const ushort_t* __restrict__ integb,
               float* __restrict__ rowm, float* __restrict__ rowr,
               float* __restrict__ Apart)
{
    const int b = blockIdx.x, qq = blockIdx.y, t = threadIdx.x;
    const int l = t & 63, w = t >> 6;
    const int n0 = qq*49;
    float4 acc[5];
    #pragma unroll
    for (int ch=0; ch<5; ++ch) acc[ch] = (float4){0.f,0.f,0.f,0.f};
    float mracc = 0.f;
    for (int n = w; n < 49; n += 4){
        const int row = b*N_ + n0 + n;
        const ushort_t* hr = hb + (size_t)row*IN_;
        float4 e[5];
        #pragma unroll
        for (int ch=0; ch<4; ++ch){
            us4 iv = *(const us4*)(hr + ch*256 + l*4);
            e[ch].x = bf2f(iv[0]); e[ch].y = bf2f(iv[1]);
            e[ch].z = bf2f(iv[2]); e[ch].w = bf2f(iv[3]);
        }
        {
            us4 iv = *(const us4*)(integb + (size_t)row*D_ + l*4);
            e[4].x = bf2f(iv[0]); e[4].y = bf2f(iv[1]);
            e[4].z = bf2f(iv[2]); e[4].w = bf2f(iv[3]);
        }
        float s = 0.f, s2 = 0.f;
        #pragma unroll
        for (int ch=0; ch<5; ++ch){
            s  += e[ch].x + e[ch].y + e[ch].z + e[ch].w;
            s2 += e[ch].x*e[ch].x + e[ch].y*e[ch].y + e[ch].z*e[ch].z + e[ch].w*e[ch].w;
        }
        #pragma unroll
        for (int off=32; off>0; off>>=1){ s += __shfl_xor(s, off); s2 += __shfl_xor(s2, off); }
        float m  = s * (1.0f/CAT);
        float rr = rsqrtf(s2 * (1.0f/CAT) - m*m + 1e-5f);
        if (l == 0){ rowm[row] = m; rowr[row] = rr; }
        #pragma unroll
        for (int ch=0; ch<5; ++ch){
            acc[ch].x += rr*e[ch].x; acc[ch].y += rr*e[ch].y;
            acc[ch].z += rr*e[ch].z; acc[ch].w += rr*e[ch].w;
        }
        mracc += rr*m;
    }
    __shared__ float part[4][CAT];
    __shared__ float pm[4];
    #pragma unroll
    for (int ch=0; ch<4; ++ch) *(float4*)&part[w][ch*256 + l*4] = acc[ch];
    *(float4*)&part[w][IN_ + l*4] = acc[4];
    if (l == 0) pm[w] = mracc;
    __syncthreads();
    float* ap = Apart + ((size_t)b*4 + qq)*APLD;
    for (int c = t; c < 1280; c += 256)
        ap[c] = part[0][c] + part[1][c] + part[2][c] + part[3][c];
    if (t == 0) ap[1280] = pm[0] + pm[1] + pm[2] + pm[3];
}

// ---------- fused tail1: (b<256) Abar-reduce + pooled; (b>=256) se-mean ----------
__global__ __launch_bounds__(256)
void tail1_kernel(const float* __restrict__ Apart,
                  const float* __restrict__ Wfs, const float* __restrict__ wsum,
                  const float* __restrict__ bfs,
                  const ushort_t* __restrict__ seb,
                  float* __restrict__ pooled, float* __restrict__ sp)
{
    const int b0 = blockIdx.x, t = threadIdx.x;
    if (b0 < 256){
        const int b = b0;
        __shared__ float ab[CAT];
        __shared__ float mb;
        const float* ap = Apart + (size_t)b*4*APLD;
        for (int c = t; c < 1280; c += 256)
            ab[c] = (ap[c] + ap[APLD+c] + ap[2*APLD+c] + ap[3*APLD+c]) * (1.f/N_);
        if (t == 0)
            mb = (ap[1280] + ap[APLD+1280] + ap[2*APLD+1280] + ap[3*APLD+1280]) * (1.f/N_);
        __syncthreads();
        const int d = t;
        const float* w = Wfs + (size_t)d*CAT;
        float s = 0.f;
        for (int c=0;c<CAT;c+=4){
            float4 wv = *(const float4*)(w+c);
            s += ab[c]*wv.x + ab[c+1]*wv.y + ab[c+2]*wv.z + ab[c+3]*wv.w;
        }
        pooled[b*D_ + d] = s - mb*wsum[d] + bfs[d];
    } else {
        const int b = b0 - 256, d = t;
        const ushort_t* p = seb + (size_t)b*N_*D_ + d;
        float s = 0.f;
        for (int n=0;n<N_;++n) s += bf2f(p[(size_t)n*D_]);
        sp[b*D_ + d] = s * (1.0f/N_);
    }
}

// ---------- fused parent logits + routing + child classifiers ----------
__global__ __launch_bounds__(256)
void parent_child_kernel(const float* __restrict__ pooled, const float* __restrict__ Wpc,
                         const float* __restrict__ bpc, const float* __restrict__ sp,
                         const float* __restrict__ Wc0, const float* __restrict__ bc0,
                         const float* __restrict__ Wc1, const float* __restrict__ bc1,
                         float* __restrict__ out, float* __restrict__ out_c0,
                         float* __restrict__ out_c1)
{
    const int b = blockIdx.x, t = threadIdx.x;
    __shared__ __align__(16) float pl[D_];
    __shared__ float spl[D_];
    __shared__ float lg[NC_];
    pl[t]  = pooled[b*D_ + t];
    spl[t] = sp[b*D_ + t];
    __syncthreads();
    for (int c = t; c < NC_; c += 256){
        const float4* w4 = (const float4*)(Wpc + (size_t)c*D_);
        float s = 0.f;
        #pragma unroll 16
        for (int j=0;j<64;++j){
            float4 wv = w4[j];
            s += pl[j*4]*wv.x + pl[j*4+1]*wv.y + pl[j*4+2]*wv.z + pl[j*4+3]*wv.w;
        }
        lg[c] = s + bpc[c];
    }
    __syncthreads();
    float s=0.f, s2=0.f, bmv=-3.4e38f; int bidx=0;
    for (int c=t;c<NC_;c+=256){
        float x = lg[c]; s += x; s2 += x*x;
        if (x > bmv){ bmv=x; bidx=c; }
    }
    #pragma unroll
    for (int off=32; off>0; off>>=1){
        s  += __shfl_down(s, off);
        s2 += __shfl_down(s2, off);
        float ov = __shfl_down(bmv, off); int oi = __shfl_down(bidx, off);
        if (ov > bmv || (ov == bmv && oi < bidx)){ bmv=ov; bidx=oi; }
    }
    __shared__ float rs[4], rs2[4], rmv[4]; __shared__ int ri[4];
    __shared__ float fm, fr_; __shared__ int ymy;
    int w = t >> 6;
    if ((t & 63) == 0){ rs[w]=s; rs2[w]=s2; rmv[w]=bmv; ri[w]=bidx; }
    __syncthreads();
    if (t == 0){
        float S=0.f, S2=0.f, mv=-3.4e38f; int mi=0;
        for (int i=0;i<4;++i){
            S += rs[i]; S2 += rs2[i];
            if (rmv[i] > mv || (rmv[i] == mv && ri[i] < mi)){ mv=rmv[i]; mi=ri[i]; }
        }
        float mean = S*(1.0f/NC_);
        float var  = S2*(1.0f/NC_) - mean*mean;
        fm = mean; fr_ = rsqrtf(var + 1e-5f);
        ymy = mi;
    }
    __syncthreads();
    for (int c=t;c<NC_;c+=256) out[(size_t)b*NC_ + c] = (lg[c]-fm)*fr_;

    // ---- child classifiers (routed by ymy) ----
    const int y = ymy;
    __shared__ float c0v[S0_], c1v[S1_];
    if (t < S0_){
        const float* wp0 = Wc0 + (size_t)y*D_*S0_ + t;
        float acc = 0.f;
        for (int d=0;d<D_;++d) acc += spl[d]*wp0[(size_t)d*S0_];
        c0v[t] = acc + bc0[y*S0_ + t];
    } else if (t < S0_+S1_){
        int k = t - S0_;
        const float* wp1 = Wc1 + (size_t)y*D_*S1_ + k;
        float acc = 0.f;
        for (int d=0;d<D_;++d) acc += spl[d]*wp1[(size_t)d*S1_];
        c1v[k] = acc + bc1[y*S1_ + k];
    }
    __syncthreads();
    __shared__ float st[4];
    if (t == 0){
        float m=0.f; for (int i=0;i<S0_;++i) m += c0v[i]; m *= (1.0f/S0_);
        float v=0.f; for (int i=0;i<S0_;++i){ float d=c0v[i]-m; v += d*d; } v *= (1.0f/S0_);
        st[0]=m; st[1]=rsqrtf(v+1e-5f);
        m=0.f; for (int i=0;i<S1_;++i) m += c1v[i]; m *= (1.0f/S1_);
        v=0.f; for (int i=0;i<S1_;++i){ float d=c1v[i]-m; v += d*d; } v *= (1.0f/S1_);
        st[2]=m; st[3]=rsqrtf(v+1e-5f);
    }
    __syncthreads();
    if (t < S0_) out_c0[b*S0_ + t] = (c0v[t]-st[0])*st[1];
    else if (t < S0_+S1_) out_c1[b*S1_ + (t-S0_)] = (c1v[t-S0_]-st[2])*st[3];
}

extern "C" void kernel_launch(void* const* d_in, const int* in_sizes, int n_in,
                              void* d_out, int out_size, void* d_ws, size_t ws_size,
                              hipStream_t stream)
{
    const float* h   = (const float*)d_in[0];
    const float* Wp  = (const float*)d_in[1];
    const float* bp  = (const float*)d_in[2];
    const float* Wsub= (const float*)d_in[3];
    const float* bs  = (const float*)d_in[4];
    const float* Wq  = (const float*)d_in[5];
    const float* bq  = (const float*)d_in[6];
    const float* Wk  = (const float*)d_in[7];
    const float* bk  = (const float*)d_in[8];
    const float* Wv  = (const float*)d_in[9];
    const float* bv  = (const float*)d_in[10];
    const float* Wo  = (const float*)d_in[11];
    const float* bo  = (const float*)d_in[12];
    const float* Wfs = (const float*)d_in[13];
    const float* bfs = (const float*)d_in[14];
    const float* Wpc = (const float*)d_in[15];
    const float* bpc = (const float*)d_in[16];
    const float* Wc0 = (const float*)d_in[17];
    const float* bc0 = (const float*)d_in[18];
    const float* Wc1 = (const float*)d_in[19];
    const float* bc1 = (const float*)d_in[20];

    float* out = (float*)d_out;
    float* out_pl = out;                         // [256,1000]
    float* out_c0 = out + 256000;                // [256,10]
    float* out_c1 = out + 258560;                // [256,20]
    float* out_fs = out + 263680;                // [256,196,256]
    float* out_se = out + 13108736;              // [256,196,256]

    // ---- workspace: 8 bf16 units (slots 0-3 = hb, 4-7 time-shared) ----
    ushort_t* U = (ushort_t*)d_ws;
    const size_t UN = (size_t)ROWS * D_;         // 12,845,056
    ushort_t* hb   = U + 0*UN;                   // bf16(h), spans 4 UN
    ushort_t* s4   = U + 4*UN;                   // pe
    ushort_t* s5   = U + 5*UN;                   // se (K and V for attn)
    ushort_t* s6   = U + 6*UN;                   // q'' -> integ
    ushort_t* s7   = U + 7*UN;                   // ao'

    float* fmisc = (float*)(U + 8*UN);
    float* rowm = fmisc;                          // 50176
    float* rowr = rowm + ROWS;                    // 50176
    float* wsmb = rowr + ROWS;                    // 256
    float* pooled = wsmb + D_;                    // 65536
    float* sp   = pooled + (size_t)B_*D_;         // 65536
    float* bqk  = sp + (size_t)B_*D_;             // 256
    float* bvo  = bqk + 256;                      // 256
    float* Apart = bvo + 256;                     // 256*4*1344
    ushort_t* wp = (ushort_t*)(Apart + (size_t)B_*4*APLD);
    ushort_t* WpsH = wp;               // [512][1024]
    ushort_t* WfsH = WpsH + 524288;    // [256][1280]
    ushort_t* WqkH = WfsH + 327680;    // [256][256]
    ushort_t* WvoH = WqkH + 65536;     // [256][256]

    // fused h-convert + weight prep (incl. folded Wqk/Wvo + wsum)
    prep_all<<<28992, 256, 0, stream>>>(h, hb, Wp, Wsub, Wfs, Wq, Wk, bq, Wo, Wv, bv, bo,
                                        WpsH, WfsH, WqkH, WvoH, wsmb, bqk, bvo);

    // fused pe+se -> pe s4, se f32 out_se + bf16 s5   (grid 784)
    gemm_bf<32,32,2,7><<<784, 512, 0, stream>>>(
        hb, hb, IN_, IN_, WpsH, IN_, bp, bs,
        out_se, s4, s5, nullptr, nullptr, nullptr);
    // q'' = pe @ Wqk^T + bqk (scale folded; k never computed) -> s6   (grid 392)
    gemm_bf<8,8,1,3><<<392, 512, 0, stream>>>(
        s4, s4, D_, D_, WqkH, D_, bqk, nullptr,
        nullptr, s6, nullptr, nullptr, nullptr, nullptr);
    // attention with K = V = se  -> ao' s7
    attn_mfma<<<dim3(B_, H_), 256, 0, stream>>>(s6, s5, s5, s7);
    // integ = ao' @ Wvo^T + bvo (v never computed) -> bf16 s6   (grid 392)
    gemm_bf<8,8,1,3><<<392, 512, 0, stream>>>(
        s7, s7, D_, D_, WvoH, D_, bvo, nullptr,
        nullptr, s6, nullptr, nullptr, nullptr, nullptr);
    // fused LN stats + abar partial (bf16 h + bf16 integ)
    abar_part<<<dim3(B_,4), 256, 0, stream>>>(hb, s6, rowm, rowr, Apart);
    // fs (A = hb | integ bf16; LN folded) -> out_fs   (grid 392)
    gemm_bf<40,32,1,5><<<392, 512, 0, stream>>>(
        hb, s6, IN_, D_, WfsH, CAT, bfs, nullptr,
        out_fs, nullptr, nullptr, rowm, rowr, wsmb);
    // fused Abar-reduce+pooled (b<256) and se-mean (b>=256)
    tail1_kernel<<<512, 256, 0, stream>>>(Apart, Wfs, wsmb, bfs, s5, pooled, sp);
    // fused parent logits + routing + child classifiers
    parent_child_kernel<<<B_, 256, 0, stream>>>(pooled, Wpc, bpc, sp,
                                                Wc0, bc0, Wc1, bc1,
                                                out_pl, out_c0, out_c1);
}